// Round 5
// baseline (1065.452 us; speedup 1.0000x reference)
//
#include <hip/hip_runtime.h>
#include <hip/hip_bf16.h>
#include <hip/hip_cooperative_groups.h>

namespace cg = cooperative_groups;

typedef __hip_bfloat16 bf16;
typedef float f4v __attribute__((ext_vector_type(4)));
typedef float f2v __attribute__((ext_vector_type(2)));

__device__ __forceinline__ float lo16(unsigned u){ return __uint_as_float(u << 16); }
__device__ __forceinline__ float hi16(unsigned u){ return __uint_as_float(u & 0xffff0000u); }

// B=512, L=64, DDYN=16, DSTAT=8, H=512, C=1024, K=16, P=8, T=2, Q=3
#define Bn 512
#define Hn 512
#define Cn 1024
#define Kn 16
#define NBANK 50000
#define NIDPAD 50176   // 196*256

__device__ __forceinline__ int clamp_id(int id){
    return (id < 0) ? 0 : ((id >= NBANK) ? (NBANK - 1) : id);
}

// ---------------- ws layout (floats), 8 MB total ----------------
// A    @0        : qGEMM partial0 -> QRAW(normed) -> gate partial0 -> F1
// B    @262144   : LOCAL
// C    @524288   : refs.lo -> DONOR
// D    @786432   : refs.hi -> PROTO
// E.lo @1048576  : qGEMM partial1 -> SIM.lo -> gate partial1 -> f2 partial0
// E.hi @1310720  : qGEMM partial2 -> SIM.hi -> gate partial2 -> f2 partial1
// F    @1572864  : ints(hist/gtot/cursor/offs) -> tr partial0 -> f2 partial2
// G    @1835008  : qGEMM partial3 -> tr partial1 -> f2 partial3
#define A_OFF    0
#define B_OFF    262144
#define C_OFF    524288
#define D_OFF    786432
#define SIM_OFF  1048576
#define ELO_OFF  1048576
#define EHI_OFF  1310720
#define F_OFF    1572864
#define G_OFF2   1835008
#define WS_FLOATS 2097152

// int offsets within F region (as int*)
#define HIST_I   0
#define GTOT_I   NIDPAD
#define CURSOR_I (NIDPAD + 256)
#define OFFS_I   (2*NIDPAD + 256)

// ===================== shared phase bodies (bit-identical to proven R3) =====================

__device__ __forceinline__ void enc_body(
    int b, int t, const float* __restrict__ seq, const float* __restrict__ mask,
    const float* __restrict__ stat, const float* __restrict__ W_seq,
    const float* __restrict__ W_stat, const float* __restrict__ b_enc,
    const int* __restrict__ cand32, int c64, int* __restrict__ hist,
    float* __restrict__ ws, float* s_pool, float* s_stat)
{
    #pragma unroll
    for (int u = 0; u < 4; u++) {
        int idx = b*Cn + u*256 + t;
        atomicAdd(&hist[clamp_id(cand32[(size_t)idx << c64])], 1);
    }
    if (t < 16) {
        float acc = 0.f, ms = 0.f;
        for (int l = 0; l < 64; l++) {
            float m = mask[b*64 + l];
            ms  += m;
            acc += seq[(b*64 + l)*16 + t] * m;
        }
        s_pool[t] = acc / fmaxf(ms, 1e-6f);
    } else if (t < 24) {
        s_stat[t - 16] = stat[b*8 + (t - 16)];
    }
    __syncthreads();
    const int h0 = 2*t, h1 = 2*t + 1;
    float a0 = b_enc[h0], a1 = b_enc[h1];
    #pragma unroll
    for (int j = 0; j < 16; j++) {
        float2 wv = *(const float2*)(W_seq + j*Hn + h0);
        a0 += s_pool[j]*wv.x; a1 += s_pool[j]*wv.y;
    }
    #pragma unroll
    for (int j = 0; j < 8; j++) {
        float2 wv = *(const float2*)(W_stat + j*Hn + h0);
        a0 += s_stat[j]*wv.x; a1 += s_stat[j]*wv.y;
    }
    float* g = ws + B_OFF + (size_t)b*Hn;
    g[h0] = fmaxf(a0, 0.f); g[h1] = fmaxf(a1, 0.f);
}

__device__ __forceinline__ void scan_body(
    int v, int t, const int* __restrict__ hist, int* __restrict__ offs,
    int* __restrict__ gtot, int* __restrict__ cursor, int* s /*257 ints*/)
{
    const int g = v*256 + t;
    const int val = hist[g];
    cursor[g] = 0;
    s[t] = val; __syncthreads();
    #pragma unroll
    for (int off = 1; off < 256; off <<= 1) {
        int x = (t >= off) ? s[t - off] : 0;
        __syncthreads();
        s[t] += x;
        __syncthreads();
    }
    if (t == 255) s[256] = atomicAdd(gtot, s[255]);
    __syncthreads();
    offs[g] = s[256] + s[t] - val;
}

__device__ __forceinline__ void scatter_body(
    int i, int c64, const int* __restrict__ cand32, int* __restrict__ cursor,
    const int* __restrict__ offs, unsigned* __restrict__ refs)
{
    const int id = clamp_id(cand32[(size_t)i << c64]);
    const int pos = atomicAdd(&cursor[id], 1);
    refs[offs[id] + pos] = (unsigned)i;
}

__device__ __forceinline__ void qgemm_body(
    int ct, int rt, int kz, int t,
    const float* __restrict__ W, const float* __restrict__ bias,
    const float* __restrict__ in,
    float* __restrict__ P0, float* __restrict__ P1,
    float* __restrict__ P2, float* __restrict__ P3,
    float (*lt)[132])
{
    {   // stage 64 rows x 128 k
        int r = t >> 2, c0 = (t & 3)*32;
        const float* src = in + (size_t)(rt*64 + r)*Hn + kz*128 + c0;
        #pragma unroll
        for (int i = 0; i < 8; i++)
            *(float4*)&lt[r][c0 + i*4] = *(const float4*)(src + i*4);
    }
    __syncthreads();
    const int col0 = ct*64 + (t & 15)*4, rbase = (t >> 4)*4;
    float acc[4][4];
    if (kz == 0) {
        float4 bv = *(const float4*)(bias + col0);
        #pragma unroll
        for (int i = 0; i < 4; i++) { acc[i][0]=bv.x; acc[i][1]=bv.y; acc[i][2]=bv.z; acc[i][3]=bv.w; }
    } else {
        #pragma unroll
        for (int i = 0; i < 4; i++) { acc[i][0]=0; acc[i][1]=0; acc[i][2]=0; acc[i][3]=0; }
    }
    const float* wp = W + (size_t)(kz*128)*Hn + col0;
    #pragma unroll 4
    for (int k = 0; k < 128; k++) {
        float4 wv = *(const float4*)(wp + (size_t)k*Hn);
        #pragma unroll
        for (int i = 0; i < 4; i++) {
            float a = lt[rbase + i][k];
            acc[i][0] += a*wv.x; acc[i][1] += a*wv.y; acc[i][2] += a*wv.z; acc[i][3] += a*wv.w;
        }
    }
    float* outp = (kz == 0) ? P0 : (kz == 1) ? P1 : (kz == 2) ? P2 : P3;
    #pragma unroll
    for (int i = 0; i < 4; i++) {
        float* op = outp + (size_t)(rt*64 + rbase + i)*Hn + col0;
        *(float4*)op = make_float4(acc[i][0], acc[i][1], acc[i][2], acc[i][3]);
    }
}

__device__ __forceinline__ void qnorm_body(int b, int lane, float* __restrict__ ws)
{
    const size_t o = (size_t)b*Hn + lane*8;
    const float* p0 = ws + A_OFF   + o;
    const float* p1 = ws + ELO_OFF + o;
    const float* p2 = ws + EHI_OFF + o;
    const float* p3 = ws + G_OFF2  + o;
    float4 qa, qb;
    {
        float4 a0 = *(const float4*)p0, a1 = *(const float4*)p1,
               a2 = *(const float4*)p2, a3 = *(const float4*)p3;
        qa = make_float4(((a0.x+a1.x)+a2.x)+a3.x, ((a0.y+a1.y)+a2.y)+a3.y,
                         ((a0.z+a1.z)+a2.z)+a3.z, ((a0.w+a1.w)+a2.w)+a3.w);
        float4 b0 = *(const float4*)(p0+4), b1 = *(const float4*)(p1+4),
               b2 = *(const float4*)(p2+4), b3 = *(const float4*)(p3+4);
        qb = make_float4(((b0.x+b1.x)+b2.x)+b3.x, ((b0.y+b1.y)+b2.y)+b3.y,
                         ((b0.z+b1.z)+b2.z)+b3.z, ((b0.w+b1.w)+b2.w)+b3.w);
    }
    float ss = qa.x*qa.x + qa.y*qa.y + qa.z*qa.z + qa.w*qa.w
             + qb.x*qb.x + qb.y*qb.y + qb.z*qb.z + qb.w*qb.w;
    #pragma unroll
    for (int o2 = 32; o2; o2 >>= 1) ss += __shfl_xor(ss, o2);
    float inv = 1.f / fmaxf(sqrtf(ss), 1e-12f);
    qa.x *= inv; qa.y *= inv; qa.z *= inv; qa.w *= inv;
    qb.x *= inv; qb.y *= inv; qb.z *= inv; qb.w *= inv;
    float* qr = ws + A_OFF + o;
    *(float4*)qr = qa; *(float4*)(qr + 4) = qb;
}

// ---- dotinv (R3 proven): nt key stream, predicated tail, 2-stage pipeline ----
#define DI_LOAD(R0,R1,R2,R3,A0,Bq0,A1,Bq1,A2,Bq2,A3,Bq3,BASE) do {                       \
    int j0_=(BASE), j1_=(BASE)+1, j2_=(BASE)+2, j3_=(BASE)+3;                            \
    const int m_ = n - 1;                                                                \
    const int c1_ = (j1_ < n), c2_ = (j2_ < n), c3_ = (j3_ < n);                         \
    j0_ = j0_>m_?m_:j0_; j1_ = j1_>m_?m_:j1_; j2_ = j2_>m_?m_:j2_; j3_ = j3_>m_?m_:j3_;  \
    R0 = (j0_<64)?(unsigned)__shfl((int)refv,j0_):__builtin_nontemporal_load(refs+start+j0_); \
    R1 = (j1_<64)?(unsigned)__shfl((int)refv,j1_):__builtin_nontemporal_load(refs+start+j1_); \
    R2 = (j2_<64)?(unsigned)__shfl((int)refv,j2_):__builtin_nontemporal_load(refs+start+j2_); \
    R3 = (j3_<64)?(unsigned)__shfl((int)refv,j3_):__builtin_nontemporal_load(refs+start+j3_); \
    {   const float* q0_ = qbase + (size_t)(R0>>10)*Hn + lane*8;                         \
        A0 = *(const float4*)q0_; Bq0 = *(const float4*)(q0_+4); }                       \
    if (c1_) { const float* q1_ = qbase + (size_t)(R1>>10)*Hn + lane*8;                  \
        A1 = *(const float4*)q1_; Bq1 = *(const float4*)(q1_+4); }                       \
    if (c2_) { const float* q2_ = qbase + (size_t)(R2>>10)*Hn + lane*8;                  \
        A2 = *(const float4*)q2_; Bq2 = *(const float4*)(q2_+4); }                       \
    if (c3_) { const float* q3_ = qbase + (size_t)(R3>>10)*Hn + lane*8;                  \
        A3 = *(const float4*)q3_; Bq3 = *(const float4*)(q3_+4); }                       \
} while(0)

#define DI_COMP(R0,R1,R2,R3,A0,Bq0,A1,Bq1,A2,Bq2,A3,Bq3,BASE) do {                       \
    float s0_ = ka.x*A0.x + ka.y*A0.y + ka.z*A0.z + ka.w*A0.w                            \
              + kb.x*Bq0.x + kb.y*Bq0.y + kb.z*Bq0.z + kb.w*Bq0.w;                       \
    float s1_ = ka.x*A1.x + ka.y*A1.y + ka.z*A1.z + ka.w*A1.w                            \
              + kb.x*Bq1.x + kb.y*Bq1.y + kb.z*Bq1.z + kb.w*Bq1.w;                       \
    float s2_ = ka.x*A2.x + ka.y*A2.y + ka.z*A2.z + ka.w*A2.w                            \
              + kb.x*Bq2.x + kb.y*Bq2.y + kb.z*Bq2.z + kb.w*Bq2.w;                       \
    float s3_ = ka.x*A3.x + ka.y*A3.y + ka.z*A3.z + ka.w*A3.w                            \
              + kb.x*Bq3.x + kb.y*Bq3.y + kb.z*Bq3.z + kb.w*Bq3.w;                       \
    s0_ += __shfl_xor(s0_,32); s1_ += __shfl_xor(s1_,32);                                \
    s2_ += __shfl_xor(s2_,32); s3_ += __shfl_xor(s3_,32);                                \
    s0_ += __shfl_xor(s0_,16); s1_ += __shfl_xor(s1_,16);                                \
    s2_ += __shfl_xor(s2_,16); s3_ += __shfl_xor(s3_,16);                                \
    s0_ += __shfl_xor(s0_, 8); s1_ += __shfl_xor(s1_, 8);                                \
    s2_ += __shfl_xor(s2_, 8); s3_ += __shfl_xor(s3_, 8);                                \
    int d_ = (lane >> 3) & 3;                                                            \
    float t_ = d_==0 ? s0_ : d_==1 ? s1_ : d_==2 ? s2_ : s3_;                            \
    t_ += __shfl_xor(t_, 4); t_ += __shfl_xor(t_, 2); t_ += __shfl_xor(t_, 1);           \
    if ((lane & 7) == 0 && lane < 32) {                                                  \
        int dd_ = lane >> 3;                                                             \
        if ((BASE) + dd_ < n) {                                                          \
            unsigned rs_ = dd_==0 ? R0 : dd_==1 ? R1 : dd_==2 ? R2 : R3;                 \
            simw[rs_] = t_;                                                              \
        }                                                                                \
    }                                                                                    \
} while(0)

__device__ __forceinline__ void dotinv_wave(
    int id, int lane, const float* __restrict__ bank_keys,
    const unsigned* __restrict__ refs, const int* __restrict__ offs,
    const int* __restrict__ cnt, const float* __restrict__ qbase,
    float* __restrict__ simw)
{
    const int n = cnt[id];
    if (n <= 0) return;
    const int start = offs[id];

    const float* kp = bank_keys + (size_t)id*Hn + lane*8;
    f4v kav = __builtin_nontemporal_load((const f4v*)kp);
    f4v kbv = __builtin_nontemporal_load((const f4v*)(kp + 4));
    float4 ka = make_float4(kav.x, kav.y, kav.z, kav.w);
    float4 kb = make_float4(kbv.x, kbv.y, kbv.z, kbv.w);
    const unsigned refv = refs[start + (lane < n ? lane : n - 1)];

    unsigned Ar0,Ar1,Ar2,Ar3, Br0=0,Br1=0,Br2=0,Br3=0;
    float4 Aa0,Ab0,Aa1,Ab1,Aa2,Ab2,Aa3,Ab3;
    float4 Ba0,Bb0,Ba1,Bb1,Ba2,Bb2,Ba3,Bb3;
    Aa0=Ab0=Aa1=Ab1=Aa2=Ab2=Aa3=Ab3=make_float4(0.f,0.f,0.f,0.f);
    Ba0=Bb0=Ba1=Bb1=Ba2=Bb2=Ba3=Bb3=make_float4(0.f,0.f,0.f,0.f);

    DI_LOAD(Ar0,Ar1,Ar2,Ar3, Aa0,Ab0,Aa1,Ab1,Aa2,Ab2,Aa3,Ab3, 0);
    for (int base = 0; ; ) {
        if (base + 4 < n) DI_LOAD(Br0,Br1,Br2,Br3, Ba0,Bb0,Ba1,Bb1,Ba2,Bb2,Ba3,Bb3, base + 4);
        DI_COMP(Ar0,Ar1,Ar2,Ar3, Aa0,Ab0,Aa1,Ab1,Aa2,Ab2,Aa3,Ab3, base);
        if (base + 8 < n) DI_LOAD(Ar0,Ar1,Ar2,Ar3, Aa0,Ab0,Aa1,Ab1,Aa2,Ab2,Aa3,Ab3, base + 8);
        DI_COMP(Br0,Br1,Br2,Br3, Ba0,Bb0,Ba1,Bb1,Ba2,Bb2,Ba3,Bb3, base + 4);
        base += 8;
        if (base >= n) break;
    }
}

// ---- select shared-state struct ----
struct SelS {
    float s_sim[Cn];
    float s_bv[4]; int s_bi[4];
    float s_topv[Kn]; int s_sel[Kn];
    float s_w[Kn];
    float s_score[8], s_pw[8];
};

__device__ __forceinline__ void select_body(
    int b, int t, const float* __restrict__ bank_values,
    const int* __restrict__ cand32, int c64, const float* __restrict__ proto,
    float* __restrict__ ws, SelS* S)
{
    const int w = t >> 6, lane = t & 63;
    const int h0 = 2*t, h1 = 2*t + 1;

    *(float4*)&S->s_sim[t*4] = *(const float4*)(ws + SIM_OFF + (size_t)b*Cn + t*4);

    const float* qr = ws + A_OFF + (size_t)b*Hn + lane*8;
    float4 qa = *(const float4*)qr, qb = *(const float4*)(qr + 4);
    float qv[8] = {qa.x, qa.y, qa.z, qa.w, qb.x, qb.y, qb.z, qb.w};
    __syncthreads();

    for (int k = 0; k < Kn; k++) {
        float best = -1e30f; int bi = 0x7fffffff;
        for (int i = t; i < Cn; i += 256) {
            float v = S->s_sim[i];
            if (v > best || (v == best && i < bi)) { best = v; bi = i; }
        }
        #pragma unroll
        for (int o = 32; o; o >>= 1) {
            float ov = __shfl_xor(best, o); int oi = __shfl_xor(bi, o);
            if (ov > best || (ov == best && oi < bi)) { best = ov; bi = oi; }
        }
        if (lane == 0) { S->s_bv[w] = best; S->s_bi[w] = bi; }
        __syncthreads();
        if (t == 0) {
            float bv = S->s_bv[0]; int bbi = S->s_bi[0];
            for (int x = 1; x < 4; x++)
                if (S->s_bv[x] > bv || (S->s_bv[x] == bv && S->s_bi[x] < bbi)) { bv = S->s_bv[x]; bbi = S->s_bi[x]; }
            if (bbi < 0 || bbi >= Cn) bbi = 0;
            S->s_topv[k] = bv; S->s_sel[k] = bbi; S->s_sim[bbi] = -1e30f;
        }
        __syncthreads();
    }

    if (t == 0) {
        float m = S->s_topv[0];
        float e[Kn], ssum = 0.f;
        for (int k = 0; k < Kn; k++) { e[k] = __expf((S->s_topv[k] - m) * 5.0f); ssum += e[k]; }
        float inv = 1.f / ssum;
        for (int k = 0; k < Kn; k++) S->s_w[k] = e[k] * inv;
    }
    for (int p = w; p < 8; p += 4) {
        const float* pp = proto + (size_t)p*Hn + lane*8;
        float4 pa = *(const float4*)pp, pb = *(const float4*)(pp + 4);
        float f[8] = {pa.x, pa.y, pa.z, pa.w, pb.x, pb.y, pb.z, pb.w};
        float dq = 0.f, sq = 0.f;
        #pragma unroll
        for (int i = 0; i < 8; i++) { dq += f[i]*qv[i]; sq += f[i]*f[i]; }
        #pragma unroll
        for (int o = 32; o; o >>= 1) { dq += __shfl_xor(dq, o); sq += __shfl_xor(sq, o); }
        if (lane == 0) S->s_score[p] = dq / fmaxf(sqrtf(sq), 1e-12f);
    }
    __syncthreads();
    if (t == 0) {
        float m = S->s_score[0];
        for (int p = 1; p < 8; p++) m = fmaxf(m, S->s_score[p]);
        float e[8], ssum = 0.f;
        for (int p = 0; p < 8; p++) { e[p] = __expf(S->s_score[p] - m); ssum += e[p]; }
        float inv = 1.f / ssum;
        for (int p = 0; p < 8; p++) S->s_pw[p] = e[p] * inv;
    }
    __syncthreads();

    {
        float a0 = 0.f, a1 = 0.f;
        #pragma unroll
        for (int k = 0; k < Kn; k++) {
            int id = clamp_id(cand32[(size_t)(b*Cn + S->s_sel[k]) << c64]);
            f2v v = __builtin_nontemporal_load((const f2v*)(bank_values + (size_t)id*Hn + h0));
            a0 += S->s_w[k]*v.x; a1 += S->s_w[k]*v.y;
        }
        float* gd = ws + C_OFF + (size_t)b*Hn;
        gd[h0] = a0; gd[h1] = a1;
    }
    {
        float a0 = 0.f, a1 = 0.f;
        #pragma unroll
        for (int p = 0; p < 8; p++) {
            float2 v = *(const float2*)(proto + (size_t)p*Hn + h0);
            a0 += S->s_pw[p]*v.x; a1 += S->s_pw[p]*v.y;
        }
        float* gp = ws + D_OFF + (size_t)b*Hn;
        gp[h0] = a0; gp[h1] = a1;
    }
}

__device__ __forceinline__ void gatetr_body(
    int ct, int rt, int z, int t,
    const float* __restrict__ W_tr, const float* __restrict__ b_tr,
    const float* __restrict__ W_gate, const float* __restrict__ b_gate,
    float* __restrict__ ws, float (*lt)[260])
{
    const int isGate = (z < 3);
    const int sl = isGate ? z : (z - 3);
    const float* W = isGate ? (W_gate + (size_t)(z*512)*Hn) : (W_tr + (size_t)(sl*512)*Hn);
    const float* slab = ws + B_OFF + (size_t)(isGate ? z : (sl + 1))*262144;
    float* outp = isGate
        ? ((z == 0) ? ws + A_OFF : (z == 1) ? ws + ELO_OFF : ws + EHI_OFF)
        : ((sl == 0) ? ws + F_OFF : ws + G_OFF2);

    const int col0 = ct*128 + (t & 31)*4, rbase = (t >> 5)*4;
    float acc[4][4];
    if (z == 0 || z == 3) {
        const float* bias = isGate ? b_gate : b_tr;
        float4 bv = *(const float4*)(bias + col0);
        #pragma unroll
        for (int i = 0; i < 4; i++) { acc[i][0]=bv.x; acc[i][1]=bv.y; acc[i][2]=bv.z; acc[i][3]=bv.w; }
    } else {
        #pragma unroll
        for (int i = 0; i < 4; i++) { acc[i][0]=0; acc[i][1]=0; acc[i][2]=0; acc[i][3]=0; }
    }

    #pragma unroll
    for (int h = 0; h < 2; h++) {
        if (h) __syncthreads();
        {   // stage 32 rows x 256 k
            int r = t >> 3, c0 = (t & 7)*32;
            const float* src = slab + (size_t)(rt*32 + r)*Hn + h*256 + c0;
            #pragma unroll
            for (int i = 0; i < 8; i++)
                *(float4*)&lt[r][c0 + i*4] = *(const float4*)(src + i*4);
        }
        __syncthreads();
        const float* wp = W + (size_t)(h*256)*Hn + col0;
        #pragma unroll 4
        for (int k = 0; k < 256; k++) {
            float4 wv = *(const float4*)(wp + (size_t)k*Hn);
            #pragma unroll
            for (int i = 0; i < 4; i++) {
                float a = lt[rbase + i][k];
                acc[i][0] += a*wv.x; acc[i][1] += a*wv.y; acc[i][2] += a*wv.z; acc[i][3] += a*wv.w;
            }
        }
    }
    #pragma unroll
    for (int i = 0; i < 4; i++) {
        float* op = outp + (size_t)(rt*32 + rbase + i)*Hn + col0;
        *(float4*)op = make_float4(acc[i][0], acc[i][1], acc[i][2], acc[i][3]);
    }
}

__device__ __forceinline__ void f1ew_body(int i4, float* __restrict__ ws)
{
    const size_t off = (size_t)(i4 >> 7)*Hn + (i4 & 127)*4;
    float4 lc = *(const float4*)(ws + B_OFF + off);
    float4 g0 = *(const float4*)(ws + A_OFF + off);
    float4 g1 = *(const float4*)(ws + ELO_OFF + off);
    float4 g2 = *(const float4*)(ws + EHI_OFF + off);
    float4 t0 = *(const float4*)(ws + F_OFF + off);
    float4 t1 = *(const float4*)(ws + G_OFF2 + off);
    float4 ga = make_float4((g0.x+g1.x)+g2.x, (g0.y+g1.y)+g2.y,
                            (g0.z+g1.z)+g2.z, (g0.w+g1.w)+g2.w);
    float4 tr = make_float4(t0.x+t1.x, t0.y+t1.y, t0.z+t1.z, t0.w+t1.w);
    float4 r;
    float s;
    s = 1.f/(1.f + __expf(-ga.x)); r.x = s*lc.x + (1.f-s)*fmaxf(tr.x, 0.f);
    s = 1.f/(1.f + __expf(-ga.y)); r.y = s*lc.y + (1.f-s)*fmaxf(tr.y, 0.f);
    s = 1.f/(1.f + __expf(-ga.z)); r.z = s*lc.z + (1.f-s)*fmaxf(tr.z, 0.f);
    s = 1.f/(1.f + __expf(-ga.w)); r.w = s*lc.w + (1.f-s)*fmaxf(tr.w, 0.f);
    *(float4*)(ws + A_OFF + off) = r;
}

__device__ __forceinline__ void heads_body(
    int b, int lane, const float* __restrict__ W_quant, const float* __restrict__ b_quant,
    const float* __restrict__ W_ev, const float* __restrict__ b_ev,
    const float* __restrict__ ws_ro, float* __restrict__ out)
{
    const size_t o = (size_t)b*Hn + lane*8;
    const float* p0 = ws_ro + ELO_OFF + o;
    const float* p1 = ws_ro + EHI_OFF + o;
    const float* p2 = ws_ro + F_OFF + o;
    const float* p3 = ws_ro + G_OFF2 + o;
    float4 a0 = *(const float4*)p0, a1 = *(const float4*)p1,
           a2 = *(const float4*)p2, a3 = *(const float4*)p3;
    float4 b0 = *(const float4*)(p0+4), b1 = *(const float4*)(p1+4),
           b2 = *(const float4*)(p2+4), b3 = *(const float4*)(p3+4);
    float fv[8] = {
        fmaxf(((a0.x+a1.x)+a2.x)+a3.x, 0.f), fmaxf(((a0.y+a1.y)+a2.y)+a3.y, 0.f),
        fmaxf(((a0.z+a1.z)+a2.z)+a3.z, 0.f), fmaxf(((a0.w+a1.w)+a2.w)+a3.w, 0.f),
        fmaxf(((b0.x+b1.x)+b2.x)+b3.x, 0.f), fmaxf(((b0.y+b1.y)+b2.y)+b3.y, 0.f),
        fmaxf(((b0.z+b1.z)+b2.z)+b3.z, 0.f), fmaxf(((b0.w+b1.w)+b2.w)+b3.w, 0.f)};
    float acc[8];
    #pragma unroll
    for (int q = 0; q < 8; q++) acc[q] = 0.f;
    #pragma unroll
    for (int i = 0; i < 8; i++) {
        int h = lane*8 + i;
        float fh = fv[i];
        acc[0] += fh*W_quant[(0*Hn + h)*3 + 0];
        acc[1] += fh*W_quant[(0*Hn + h)*3 + 1];
        acc[2] += fh*W_quant[(0*Hn + h)*3 + 2];
        acc[3] += fh*W_quant[(1*Hn + h)*3 + 0];
        acc[4] += fh*W_quant[(1*Hn + h)*3 + 1];
        acc[5] += fh*W_quant[(1*Hn + h)*3 + 2];
        acc[6] += fh*W_ev[0*Hn + h];
        acc[7] += fh*W_ev[1*Hn + h];
    }
    #pragma unroll
    for (int q = 0; q < 8; q++) {
        #pragma unroll
        for (int s = 32; s; s >>= 1) acc[q] += __shfl_xor(acc[q], s);
    }
    if (lane == 0) {
        float qv[6];
        for (int q = 0; q < 6; q++) qv[q] = acc[q] + b_quant[q];
        #pragma unroll
        for (int tt = 0; tt < 2; tt++) {
            float a = qv[tt*3], bb = qv[tt*3+1], c = qv[tt*3+2];
            float mn = fminf(a, fminf(bb, c)), mx = fmaxf(a, fmaxf(bb, c));
            float md = a + bb + c - mn - mx;
            qv[tt*3] = mn; qv[tt*3+1] = md; qv[tt*3+2] = mx;
        }
        for (int q = 0; q < 6; q++) out[b*8 + q] = qv[q];
        out[b*8 + 6] = acc[6] + b_ev[0];
        out[b*8 + 7] = acc[7] + b_ev[1];
    }
}

// ===================== cooperative mega-kernels =====================

#define COOP_SMEM 33792   // max(qgemm 64*132*4, gatetr 32*260*4, SelS, scan)

__global__ __launch_bounds__(256, 4) void k_coopA(
    const float* __restrict__ seq, const float* __restrict__ mask, const float* __restrict__ stat,
    const float* __restrict__ W_seq, const float* __restrict__ W_stat, const float* __restrict__ b_enc,
    const int* __restrict__ cand32, const float* __restrict__ W_q, const float* __restrict__ b_q,
    const float* __restrict__ bank_keys, float* __restrict__ ws)
{
    cg::grid_group grid = cg::this_grid();
    const int bid = blockIdx.x, nb = gridDim.x, t = threadIdx.x;
    __shared__ __align__(16) char smem[COOP_SMEM];

    int* iws = (int*)(ws + F_OFF);
    int* hist   = iws + HIST_I;
    int* gtot   = iws + GTOT_I;
    int* cursor = iws + CURSOR_I;
    int* offs   = iws + OFFS_I;
    unsigned* refs = (unsigned*)(ws + C_OFF);
    const int c64 = ((cand32[1] | cand32[3] | cand32[5] | cand32[7]) == 0) ? 1 : 0;

    // P0: zero hist + gtot
    for (int i = bid*256 + t; i < NIDPAD + 256; i += nb*256) hist[i] = 0;
    grid.sync();

    // P1: encoder + histogram
    {
        float* s_pool = (float*)smem;
        float* s_stat = (float*)(smem + 64);
        for (int b = bid; b < Bn; b += nb) {
            enc_body(b, t, seq, mask, stat, W_seq, W_stat, b_enc, cand32, c64, hist, ws, s_pool, s_stat);
            __syncthreads();
        }
    }
    grid.sync();

    // P2: qgemm (QRAW partials)
    {
        float (*lt)[132] = (float(*)[132])smem;
        for (int v = bid; v < 256; v += nb) {
            qgemm_body(v & 7, (v >> 3) & 7, v >> 6, t, W_q, b_q, ws + B_OFF,
                       ws + A_OFF, ws + ELO_OFF, ws + EHI_OFF, ws + G_OFF2, lt);
            __syncthreads();
        }
    }
    grid.sync();

    // P3: scan (v<196) + qnorm (196<=v<324)
    {
        int* s_scan = (int*)smem;
        for (int v = bid; v < 324; v += nb) {
            if (v < 196) scan_body(v, t, hist, offs, gtot, cursor, s_scan);
            else         qnorm_body((v - 196)*4 + (t >> 6), t & 63, ws);
            __syncthreads();
        }
    }
    grid.sync();

    // P4: scatter
    for (int v = bid; v < 2048; v += nb) {
        scatter_body(v*256 + t, c64, cand32, cursor, offs, refs);
    }
    grid.sync();

    // P5: dotinv (round-3 proven body)
    {
        const float* qbase = ws + A_OFF;
        float* simw = ws + SIM_OFF;
        const int lane = t & 63;
        for (int v = bid; v < 12500; v += nb) {
            dotinv_wave(v*4 + (t >> 6), lane, bank_keys, refs, offs, hist, qbase, simw);
        }
    }
}

__global__ __launch_bounds__(256, 4) void k_coopB(
    const float* __restrict__ bank_values, const int* __restrict__ cand32,
    const float* __restrict__ proto,
    const float* __restrict__ W_tr, const float* __restrict__ b_tr,
    const float* __restrict__ W_gate, const float* __restrict__ b_gate,
    const float* __restrict__ W_out, const float* __restrict__ b_out,
    const float* __restrict__ W_quant, const float* __restrict__ b_quant,
    const float* __restrict__ W_ev, const float* __restrict__ b_ev,
    float* __restrict__ ws, float* __restrict__ out)
{
    cg::grid_group grid = cg::this_grid();
    const int bid = blockIdx.x, nb = gridDim.x, t = threadIdx.x;
    __shared__ __align__(16) char smem[COOP_SMEM];
    const int c64 = ((cand32[1] | cand32[3] | cand32[5] | cand32[7]) == 0) ? 1 : 0;

    // P0: select
    {
        SelS* S = (SelS*)smem;
        for (int b = bid; b < Bn; b += nb) {
            select_body(b, t, bank_values, cand32, c64, proto, ws, S);
            __syncthreads();
        }
    }
    grid.sync();

    // P1: gate/tr partials
    {
        float (*lt)[260] = (float(*)[260])smem;
        for (int v = bid; v < 320; v += nb) {
            gatetr_body(v & 3, (v >> 2) & 15, v >> 6, t, W_tr, b_tr, W_gate, b_gate, ws, lt);
            __syncthreads();
        }
    }
    grid.sync();

    // P2: f1 elementwise
    for (int i4 = bid*256 + t; i4 < 65536; i4 += nb*256) f1ew_body(i4, ws);
    grid.sync();

    // P3: qgemm (F2 partials)
    {
        float (*lt)[132] = (float(*)[132])smem;
        for (int v = bid; v < 256; v += nb) {
            qgemm_body(v & 7, (v >> 3) & 7, v >> 6, t, W_out, b_out, ws + A_OFF,
                       ws + ELO_OFF, ws + EHI_OFF, ws + F_OFF, ws + G_OFF2, lt);
            __syncthreads();
        }
    }
    grid.sync();

    // P4: heads
    for (int b = bid; b < Bn; b += nb) {
        if (t < 64) heads_body(b, t, W_quant, b_quant, W_ev, b_ev, ws, out);
    }
}

// ===================== standalone kernels (round-3 fallback path) =====================

__global__ __launch_bounds__(256) void k_enc(
    const float* __restrict__ seq, const float* __restrict__ mask, const float* __restrict__ stat,
    const float* __restrict__ W_seq, const float* __restrict__ W_stat, const float* __restrict__ b_enc,
    const int* __restrict__ cand32, float* __restrict__ ws)
{
    __shared__ float s_pool[16], s_stat[8];
    const int c64 = ((cand32[1] | cand32[3] | cand32[5] | cand32[7]) == 0) ? 1 : 0;
    int* hist = (int*)(ws + F_OFF) + HIST_I;
    enc_body(blockIdx.x, threadIdx.x, seq, mask, stat, W_seq, W_stat, b_enc,
             cand32, c64, hist, ws, s_pool, s_stat);
}

__global__ __launch_bounds__(256) void k_scan(
    const int* __restrict__ hist, int* __restrict__ offs, int* __restrict__ gtot,
    int* __restrict__ cursor)
{
    __shared__ int s[257];
    scan_body(blockIdx.x, threadIdx.x, hist, offs, gtot, cursor, s);
}

__global__ __launch_bounds__(256) void k_scatter(
    const int* __restrict__ cand32, int* __restrict__ cursor,
    const int* __restrict__ offs, unsigned* __restrict__ refs)
{
    const int c64 = ((cand32[1] | cand32[3] | cand32[5] | cand32[7]) == 0) ? 1 : 0;
    scatter_body(blockIdx.x*256 + threadIdx.x, c64, cand32, cursor, offs, refs);
}

__global__ __launch_bounds__(256) void k_qgemm_p(
    const float* __restrict__ W, const float* __restrict__ bias,
    const float* __restrict__ in,
    float* __restrict__ P0, float* __restrict__ P1,
    float* __restrict__ P2, float* __restrict__ P3)
{
    __shared__ float lt[64][132];
    qgemm_body(blockIdx.x, blockIdx.y, blockIdx.z, threadIdx.x, W, bias, in, P0, P1, P2, P3, lt);
}

__global__ __launch_bounds__(256) void k_qnorm(float* __restrict__ ws)
{
    qnorm_body(blockIdx.x*4 + (threadIdx.x >> 6), threadIdx.x & 63, ws);
}

__global__ __launch_bounds__(256) void k_dotinv(
    const float* __restrict__ bank_keys, const unsigned* __restrict__ refs,
    const int* __restrict__ offs, const int* __restrict__ cnt,
    float* __restrict__ ws)
{
    dotinv_wave(blockIdx.x*4 + (threadIdx.x >> 6), threadIdx.x & 63,
                bank_keys, refs, offs, cnt, ws + A_OFF, ws + SIM_OFF);
}

__global__ __launch_bounds__(256) void k_select(
    const float* __restrict__ bank_values, const int* __restrict__ cand32,
    const float* __restrict__ proto, float* __restrict__ ws)
{
    __shared__ SelS S;
    const int c64 = ((cand32[1] | cand32[3] | cand32[5] | cand32[7]) == 0) ? 1 : 0;
    select_body(blockIdx.x, threadIdx.x, bank_values, cand32, c64, proto, ws, &S);
}

__global__ __launch_bounds__(256) void k_gatetr_p(
    const float* __restrict__ W_tr, const float* __restrict__ b_tr,
    const float* __restrict__ W_gate, const float* __restrict__ b_gate,
    float* __restrict__ ws)
{
    __shared__ float lt[32][260];
    gatetr_body(blockIdx.x, blockIdx.y, blockIdx.z, threadIdx.x, W_tr, b_tr, W_gate, b_gate, ws, lt);
}

__global__ __launch_bounds__(256) void k_f1ew(float* __restrict__ ws)
{
    f1ew_body(blockIdx.x*256 + threadIdx.x, ws);
}

__global__ __launch_bounds__(64) void k_heads(
    const float* __restrict__ W_quant, const float* __restrict__ b_quant,
    const float* __restrict__ W_ev, const float* __restrict__ b_ev,
    const float* __restrict__ ws_ro, float* __restrict__ out)
{
    heads_body(blockIdx.x, threadIdx.x, W_quant, b_quant, W_ev, b_ev, ws_ro, out);
}

// ===================== Fallback: proven R4 fused kernel =====================
__device__ __forceinline__ float lds_f(const void* p, int i, int f32){
    return f32 ? ((const float*)p)[i] : __bfloat162float(((const bf16*)p)[i]);
}
__device__ __forceinline__ float2 ldpair(const void* p, int elt, int f32){
    if (f32) return ((const float2*)p)[elt >> 1];
    unsigned u = ((const unsigned*)p)[elt >> 1];
    return make_float2(lo16(u), hi16(u));
}
__device__ __forceinline__ void ld8(const void* p, int elt, int f32, float* v){
    if (f32){
        const float4* q = (const float4*)((const float*)p + elt);
        float4 a = q[0], b = q[1];
        v[0]=a.x; v[1]=a.y; v[2]=a.z; v[3]=a.w; v[4]=b.x; v[5]=b.y; v[6]=b.z; v[7]=b.w;
    } else {
        uint4 u = *(const uint4*)((const bf16*)p + elt);
        v[0]=lo16(u.x); v[1]=hi16(u.x); v[2]=lo16(u.y); v[3]=hi16(u.y);
        v[4]=lo16(u.z); v[5]=hi16(u.z); v[6]=lo16(u.w); v[7]=hi16(u.w);
    }
}
__device__ __forceinline__ void st_out(void* o, int i, int f32, float v){
    if (f32) ((float*)o)[i] = v; else ((bf16*)o)[i] = __float2bfloat16(v);
}

__global__ __launch_bounds__(256) void k_fused(
    const void* __restrict__ seq, const void* __restrict__ mask, const void* __restrict__ stat,
    const void* __restrict__ bank_keys, const void* __restrict__ bank_values,
    const int* __restrict__ cand32,
    const void* __restrict__ W_seq, const void* __restrict__ W_stat, const void* __restrict__ b_enc,
    const void* __restrict__ W_q, const void* __restrict__ b_q,
    const void* __restrict__ proto,
    const void* __restrict__ W_tr, const void* __restrict__ b_tr,
    const void* __restrict__ W_gate, const void* __restrict__ b_gate,
    const void* __restrict__ W_out, const void* __restrict__ b_out,
    const void* __restrict__ W_quant, const void* __restrict__ b_quant,
    const void* __restrict__ W_ev, const void* __restrict__ b_ev,
    void* __restrict__ out)
{
    const int b = blockIdx.x, t = threadIdx.x;
    const int w = t >> 6, lane = t & 63;
    const int h0 = 2*t, h1 = 2*t + 1;
    const int f32 = (((const unsigned short*)mask)[0] == 0) ? 1 : 0;
    const int c64 = ((cand32[1] | cand32[3] | cand32[5] | cand32[7]) == 0) ? 1 : 0;

    __shared__ __align__(16) float s_pool[16];
    __shared__ __align__(16) float s_stat[8];
    __shared__ __align__(16) float g[1536];
    __shared__ __align__(16) float s_q[Hn];
    __shared__ __align__(16) float s_sim[Cn];
    __shared__ __align__(16) float f1[Hn];
    __shared__ __align__(16) float f2[Hn];
    __shared__ float s_part[4], s_ss;
    __shared__ float s_bv[4]; __shared__ int s_bi[4];
    __shared__ float s_topv[Kn]; __shared__ int s_sel[Kn];
    __shared__ float s_w[Kn];
    __shared__ float s_score[8], s_pw[8];
    __shared__ float s_head[8][4];

    if (t < 16) {
        float acc = 0.f, ms = 0.f;
        for (int l = 0; l < 64; l++) {
            float m = lds_f(mask, b*64 + l, f32);
            ms  += m;
            acc += lds_f(seq, (b*64 + l)*16 + t, f32) * m;
        }
        s_pool[t] = acc / fmaxf(ms, 1e-6f);
    } else if (t < 24) {
        s_stat[t - 16] = lds_f(stat, b*8 + (t - 16), f32);
    }
    __syncthreads();
    {
        float a0 = lds_f(b_enc, h0, f32), a1 = lds_f(b_enc, h1, f32);
        #pragma unroll
        for (int j = 0; j < 16; j++) {
            float2 wv = ldpair(W_seq, j*Hn + h0, f32);
            a0 += s_pool[j]*wv.x; a1 += s_pool[j]*wv.y;
        }
        #pragma unroll
        for (int j = 0; j < 8; j++) {
            float2 wv = ldpair(W_stat, j*Hn + h0, f32);
            a0 += s_stat[j]*wv.x; a1 += s_stat[j]*wv.y;
        }
        a0 = fmaxf(a0, 0.f); a1 = fmaxf(a1, 0.f);
        g[h0] = a0; g[h1] = a1;
    }
    __syncthreads();
    {
        float q0 = lds_f(b_q, h0, f32), q1 = lds_f(b_q, h1, f32);
        #pragma unroll 4
        for (int j = 0; j < Hn; j++) {
            float lj = g[j];
            float2 wv = ldpair(W_q, j*Hn + h0, f32);
            q0 += lj*wv.x; q1 += lj*wv.y;
        }
        float ss = q0*q0 + q1*q1;
        #pragma unroll
        for (int o = 32; o; o >>= 1) ss += __shfl_xor(ss, o);
        if (lane == 0) s_part[w] = ss;
        __syncthreads();
        if (t == 0) s_ss = s_part[0] + s_part[1] + s_part[2] + s_part[3];
        __syncthreads();
        float inv = 1.f / fmaxf(sqrtf(s_ss), 1e-12f);
        s_q[h0] = q0*inv; s_q[h1] = q1*inv;
    }
    __syncthreads();
    float qv[8];
    #pragma unroll
    for (int i = 0; i < 8; i++) qv[i] = s_q[lane*8 + i];

    for (int c0 = w*256; c0 < w*256 + 256; c0 += 4) {
        float kf[4][8];
        #pragma unroll
        for (int u = 0; u < 4; u++) {
            int id = clamp_id(cand32[(size_t)(b*Cn + c0 + u) << c64]);
            ld8(bank_keys, id*Hn + lane*8, f32, kf[u]);
        }
        #pragma unroll
        for (int u = 0; u < 4; u++) {
            float s = 0.f;
            #pragma unroll
            for (int i = 0; i < 8; i++) s += kf[u][i]*qv[i];
            #pragma unroll
            for (int o = 32; o; o >>= 1) s += __shfl_xor(s, o);
            if (lane == 0) s_sim[c0 + u] = s;
        }
    }
    __syncthreads();
    for (int k = 0; k < Kn; k++) {
        float best = -1e30f; int bi = 0x7fffffff;
        for (int i = t; i < Cn; i += 256) {
            float v = s_sim[i];
            if (v > best || (v == best && i < bi)) { best = v; bi = i; }
        }
        #pragma unroll
        for (int o = 32; o; o >>= 1) {
            float ov = __shfl_xor(best, o); int oi = __shfl_xor(bi, o);
            if (ov > best || (ov == best && oi < bi)) { best = ov; bi = oi; }
        }
        if (lane == 0) { s_bv[w] = best; s_bi[w] = bi; }
        __syncthreads();
        if (t == 0) {
            float bv = s_bv[0]; int bbi = s_bi[0];
            for (int x = 1; x < 4; x++)
                if (s_bv[x] > bv || (s_bv[x] == bv && s_bi[x] < bbi)) { bv = s_bv[x]; bbi = s_bi[x]; }
            if (bbi < 0 || bbi >= Cn) bbi = 0;
            s_topv[k] = bv; s_sel[k] = bbi; s_sim[bbi] = -1e30f;
        }
        __syncthreads();
    }
    if (t == 0) {
        float m = s_topv[0];
        float e[Kn], ssum = 0.f;
        for (int k = 0; k < Kn; k++) { e[k] = __expf((s_topv[k] - m) * 5.0f); ssum += e[k]; }
        float inv = 1.f / ssum;
        for (int k = 0; k < Kn; k++) s_w[k] = e[k] * inv;
    }
    __syncthreads();
    {
        float a0 = 0.f, a1 = 0.f;
        #pragma unroll
        for (int k = 0; k < Kn; k++) {
            int id = clamp_id(cand32[(size_t)(b*Cn + s_sel[k]) << c64]);
            float2 v = ldpair(bank_values, id*Hn + h0, f32);
            a0 += s_w[k]*v.x; a1 += s_w[k]*v.y;
        }
        g[512 + h0] = a0; g[512 + h1] = a1;
    }
    for (int p = w; p < 8; p += 4) {
        float f[8];
        ld8(proto, p*Hn + lane*8, f32, f);
        float dq = 0.f, sq = 0.f;
        #pragma unroll
        for (int i = 0; i < 8; i++) { dq += f[i]*qv[i]; sq += f[i]*f[i]; }
        #pragma unroll
        for (int o = 32; o; o >>= 1) { dq += __shfl_xor(dq, o); sq += __shfl_xor(sq, o); }
        if (lane == 0) s_score[p] = dq / fmaxf(sqrtf(sq), 1e-12f);
    }
    __syncthreads();
    if (t == 0) {
        float m = s_score[0];
        for (int p = 1; p < 8; p++) m = fmaxf(m, s_score[p]);
        float e[8], ssum = 0.f;
        for (int p = 0; p < 8; p++) { e[p] = __expf(s_score[p] - m); ssum += e[p]; }
        float inv = 1.f / ssum;
        for (int p = 0; p < 8; p++) s_pw[p] = e[p] * inv;
    }
    __syncthreads();
    {
        float a0 = 0.f, a1 = 0.f;
        #pragma unroll
        for (int p = 0; p < 8; p++) {
            float2 v = ldpair(proto, p*Hn + h0, f32);
            a0 += s_pw[p]*v.x; a1 += s_pw[p]*v.y;
        }
        g[1024 + h0] = a0; g[1024 + h1] = a1;
    }
    __syncthreads();
    float tr0 = lds_f(b_tr, h0, f32), tr1 = lds_f(b_tr, h1, f32);
    #pragma unroll 4
    for (int j = 0; j < 1024; j++) {
        float gj = g[512 + j];
        float2 wv = ldpair(W_tr, j*Hn + h0, f32);
        tr0 += gj*wv.x; tr1 += gj*wv.y;
    }
    tr0 = fmaxf(tr0, 0.f); tr1 = fmaxf(tr1, 0.f);
    float gt0 = lds_f(b_gate, h0, f32), gt1 = lds_f(b_gate, h1, f32);
    #pragma unroll 4
    for (int j = 0; j < 1536; j++) {
        float gj = g[j];
        float2 wv = ldpair(W_gate, j*Hn + h0, f32);
        gt0 += gj*wv.x; gt1 += gj*wv.y;
    }
    gt0 = 1.f/(1.f + __expf(-gt0)); gt1 = 1.f/(1.f + __expf(-gt1));
    f1[h0] = gt0*g[h0] + (1.f - gt0)*tr0;
    f1[h1] = gt1*g[h1] + (1.f - gt1)*tr1;
    __syncthreads();
    {
        float o0 = lds_f(b_out, h0, f32), o1 = lds_f(b_out, h1, f32);
        #pragma unroll 4
        for (int j = 0; j < Hn; j++) {
            float fj = f1[j];
            float2 wv = ldpair(W_out, j*Hn + h0, f32);
            o0 += fj*wv.x; o1 += fj*wv.y;
        }
        o0 = fmaxf(o0, 0.f); o1 = fmaxf(o1, 0.f);
        f2[h0] = o0; f2[h1] = o1;
    }
    __syncthreads();
    {
        float acc[8];
        #pragma unroll
        for (int o = 0; o < 8; o++) acc[o] = 0.f;
        for (int h = t; h < Hn; h += 256) {
            float fh = f2[h];
            acc[0] += fh*lds_f(W_quant, (0*Hn + h)*3 + 0, f32);
            acc[1] += fh*lds_f(W_quant, (0*Hn + h)*3 + 1, f32);
            acc[2] += fh*lds_f(W_quant, (0*Hn + h)*3 + 2, f32);
            acc[3] += fh*lds_f(W_quant, (1*Hn + h)*3 + 0, f32);
            acc[4] += fh*lds_f(W_quant, (1*Hn + h)*3 + 1, f32);
            acc[5] += fh*lds_f(W_quant, (1*Hn + h)*3 + 2, f32);
            acc[6] += fh*lds_f(W_ev, 0*Hn + h, f32);
            acc[7] += fh*lds_f(W_ev, 1*Hn + h, f32);
        }
        #pragma unroll
        for (int o = 0; o < 8; o++) {
            float v = acc[o];
            #pragma unroll
            for (int s = 32; s; s >>= 1) v += __shfl_xor(v, s);
            if (lane == 0) s_head[o][w] = v;
        }
        __syncthreads();
        if (t == 0) {
            float q[6];
            for (int o = 0; o < 6; o++)
                q[o] = s_head[o][0] + s_head[o][1] + s_head[o][2] + s_head[o][3] + lds_f(b_quant, o, f32);
            #pragma unroll
            for (int tt = 0; tt < 2; tt++) {
                float a = q[tt*3], bb = q[tt*3+1], c = q[tt*3+2];
                float mn = fminf(a, fminf(bb, c)), mx = fmaxf(a, fmaxf(bb, c));
                float md = a + bb + c - mn - mx;
                q[tt*3] = mn; q[tt*3+1] = md; q[tt*3+2] = mx;
            }
            for (int o = 0; o < 6; o++) st_out(out, b*8 + o, f32, q[o]);
            float l0 = s_head[6][0] + s_head[6][1] + s_head[6][2] + s_head[6][3] + lds_f(b_ev, 0, f32);
            float l1 = s_head[7][0] + s_head[7][1] + s_head[7][2] + s_head[7][3] + lds_f(b_ev, 1, f32);
            st_out(out, b*8 + 6, f32, l0);
            st_out(out, b*8 + 7, f32, l1);
        }
    }
}

extern "C" void kernel_launch(void* const* d_in, const int* in_sizes, int n_in,
                              void* d_out, int out_size, void* d_ws, size_t ws_size,
                              hipStream_t stream) {
    static const int expect[22] = {
        512*64*16, 512*64, 512*8, 50000*512, 50000*512, 512*1024,
        16*512, 8*512, 512, 512*512, 512, 8*512,
        1024*512, 512, 1536*512, 512, 512*512, 512,
        2*512*3, 2*3, 2*512, 2
    };
    if (n_in != 22 || out_size != 512*8) return;
    for (int i = 0; i < 22; i++) if (in_sizes[i] != expect[i]) return;

    if (ws_size < (size_t)WS_FLOATS * 4) {
        k_fused<<<Bn, 256, 0, stream>>>(
            d_in[0], d_in[1], d_in[2], d_in[3], d_in[4], (const int*)d_in[5],
            d_in[6], d_in[7], d_in[8], d_in[9], d_in[10], d_in[11],
            d_in[12], d_in[13], d_in[14], d_in[15], d_in[16], d_in[17],
            d_in[18], d_in[19], d_in[20], d_in[21], d_out);
        return;
    }

    float* ws = (float*)d_ws;
    const float* a_seq  = (const float*)d_in[0];
    const float* a_mask = (const float*)d_in[1];
    const float* a_stat = (const float*)d_in[2];
    const float* a_bk   = (const float*)d_in[3];
    const float* a_bv   = (const float*)d_in[4];
    const int*   a_cand = (const int*)d_in[5];
    const float* a_Wseq = (const float*)d_in[6];
    const float* a_Wstat= (const float*)d_in[7];
    const float* a_benc = (const float*)d_in[8];
    const float* a_Wq   = (const float*)d_in[9];
    const float* a_bq   = (const float*)d_in[10];
    const float* a_proto= (const float*)d_in[11];
    const float* a_Wtr  = (const float*)d_in[12];
    const float* a_btr  = (const float*)d_in[13];
    const float* a_Wg   = (const float*)d_in[14];
    const float* a_bg   = (const float*)d_in[15];
    const float* a_Wout = (const float*)d_in[16];
    const float* a_bout = (const float*)d_in[17];
    const float* a_Wqu  = (const float*)d_in[18];
    const float* a_bqu  = (const float*)d_in[19];
    const float* a_Wev  = (const float*)d_in[20];
    const float* a_bev  = (const float*)d_in[21];
    float* a_out = (float*)d_out;

    // ---- try cooperative 2-launch path ----
    int ncu = 0, occA = 0, occB = 0;
    int dev = 0;
    bool coop_ok = (hipGetDevice(&dev) == hipSuccess) &&
        (hipDeviceGetAttribute(&ncu, hipDeviceAttributeMultiprocessorCount, dev) == hipSuccess) &&
        (hipOccupancyMaxActiveBlocksPerMultiprocessor(&occA, k_coopA, 256, 0) == hipSuccess) &&
        (hipOccupancyMaxActiveBlocksPerMultiprocessor(&occB, k_coopB, 256, 0) == hipSuccess) &&
        (ncu >= 1) && (occA >= 1) && (occB >= 1);

    if (coop_ok) {
        int gA = occA * ncu; if (gA > 2048) gA = 2048;
        int gB = occB * ncu; if (gB > 2048) gB = 2048;
        void* argsA[] = { (void*)&a_seq, (void*)&a_mask, (void*)&a_stat,
                          (void*)&a_Wseq, (void*)&a_Wstat, (void*)&a_benc,
                          (void*)&a_cand, (void*)&a_Wq, (void*)&a_bq,
                          (void*)&a_bk, (void*)&ws };
        void* argsB[] = { (void*)&a_bv, (void*)&a_cand, (void*)&a_proto,
                          (void*)&a_Wtr, (void*)&a_btr, (void*)&a_Wg, (void*)&a_bg,
                          (void*)&a_Wout, (void*)&a_bout,
                          (void*)&a_Wqu, (void*)&a_bqu, (void*)&a_Wev, (void*)&a_bev,
                          (void*)&ws, (void*)&a_out };
        hipError_t eA = hipLaunchCooperativeKernel(k_coopA, dim3(gA), dim3(256), argsA, 0, stream);
        if (eA == hipSuccess) {
            hipError_t eB = hipLaunchCooperativeKernel(k_coopB, dim3(gB), dim3(256), argsB, 0, stream);
            if (eB == hipSuccess) return;
        }
        // fall through to separate-kernel path on failure
    }

    // ---- fallback: proven round-3 separate-kernel path ----
    int* iws = (int*)(ws + F_OFF);
    int* hist   = iws + HIST_I;
    int* gtot   = iws + GTOT_I;
    int* cursor = iws + CURSOR_I;
    int* offs   = iws + OFFS_I;
    unsigned* refs = (unsigned*)(ws + C_OFF);

    hipMemsetAsync(iws, 0, (size_t)(NIDPAD + 256)*4, stream);   // hist + gtot

    k_enc<<<Bn, 256, 0, stream>>>(a_seq, a_mask, a_stat, a_Wseq, a_Wstat, a_benc, a_cand, ws);
    k_qgemm_p<<<dim3(8, 8, 4), 256, 0, stream>>>(
        a_Wq, a_bq, ws + B_OFF, ws + A_OFF, ws + ELO_OFF, ws + EHI_OFF, ws + G_OFF2);
    k_qnorm<<<Bn/4, 256, 0, stream>>>(ws);
    k_scan<<<NIDPAD/256, 256, 0, stream>>>(hist, offs, gtot, cursor);
    k_scatter<<<(Bn*Cn)/256, 256, 0, stream>>>(a_cand, cursor, offs, refs);
    k_dotinv<<<NBANK/4, 256, 0, stream>>>(a_bk, refs, offs, hist, ws);
    k_select<<<Bn, 256, 0, stream>>>(a_bv, a_cand, a_proto, ws);
    k_gatetr_p<<<dim3(4, 16, 5), 256, 0, stream>>>(a_Wtr, a_btr, a_Wg, a_bg, ws);
    k_f1ew<<<256, 256, 0, stream>>>(ws);
    k_qgemm_p<<<dim3(8, 8, 4), 256, 0, stream>>>(
        a_Wout, a_bout, ws + A_OFF, ws + ELO_OFF, ws + EHI_OFF, ws + F_OFF, ws + G_OFF2);
    k_heads<<<Bn, 64, 0, stream>>>(a_Wqu, a_bqu, a_Wev, a_bev, ws, a_out);
}

// Round 6
// 538.531 us; speedup vs baseline: 1.9784x; 1.9784x over previous
//
#include <hip/hip_runtime.h>
#include <hip/hip_bf16.h>

typedef __hip_bfloat16 bf16;
typedef float f4v __attribute__((ext_vector_type(4)));
typedef float f2v __attribute__((ext_vector_type(2)));

__device__ __forceinline__ float lo16(unsigned u){ return __uint_as_float(u << 16); }
__device__ __forceinline__ float hi16(unsigned u){ return __uint_as_float(u & 0xffff0000u); }

// B=512, L=64, DDYN=16, DSTAT=8, H=512, C=1024, K=16, P=8, T=2, Q=3
#define Bn 512
#define Hn 512
#define Cn 1024
#define Kn 16
#define NBANK 50000
#define NIDPAD 50176   // 196*256

__device__ __forceinline__ int clamp_id(int id){
    return (id < 0) ? 0 : ((id >= NBANK) ? (NBANK - 1) : id);
}

// ---------------- ws layout (floats), 8 MB total ----------------
// A    @0        : QRAW(normed) -> gate partial0 -> F1
// B    @262144   : LOCAL
// C    @524288   : refs.lo -> DONOR
// D    @786432   : refs.hi -> PROTO
// E.lo @1048576  : SIM.lo -> gate partial1 -> f2 partial0
// E.hi @1310720  : SIM.hi -> gate partial2 -> f2 partial1
// F    @1572864  : ints(hist/gtot/cursor/offs) -> tr partial0 -> f2 partial2
// G    @1835008  : tr partial1 -> f2 partial3
#define A_OFF    0
#define B_OFF    262144
#define C_OFF    524288
#define D_OFF    786432
#define SIM_OFF  1048576
#define ELO_OFF  1048576
#define EHI_OFF  1310720
#define F_OFF    1572864
#define G_OFF2   1835008
#define WS_FLOATS 2097152

// int offsets within F region (as int*)
#define HIST_I   0
#define GTOT_I   NIDPAD
#define CURSOR_I (NIDPAD + 256)
#define OFFS_I   (2*NIDPAD + 256)   // total ints: 3*NIDPAD+256 < 262144

// ============ K1: fused encoder + histogram + qGEMM + qnorm ============
// 128 blocks x 4 rows each. W_q (1 MB) is streamed once per block with
// 4-row register reuse; local rows live in LDS. Writes LOCAL (B) + QRAW (A).
__global__ __launch_bounds__(256) void k_encq(
    const float* __restrict__ seq, const float* __restrict__ mask, const float* __restrict__ stat,
    const float* __restrict__ W_seq, const float* __restrict__ W_stat, const float* __restrict__ b_enc,
    const float* __restrict__ W_q, const float* __restrict__ b_q,
    const int* __restrict__ cand32, float* __restrict__ ws)
{
    const int b0 = blockIdx.x*4, t = threadIdx.x;
    const int w = t >> 6, lane = t & 63;
    const int h0 = 2*t, h1 = 2*t + 1;
    const int c64 = ((cand32[1] | cand32[3] | cand32[5] | cand32[7]) == 0) ? 1 : 0;

    // histogram: 4 rows x 1024 candidate ids
    {
        int* hist = (int*)(ws + F_OFF) + HIST_I;
        #pragma unroll
        for (int u = 0; u < 16; u++) {
            int idx = b0*Cn + u*256 + t;
            atomicAdd(&hist[clamp_id(cand32[(size_t)idx << c64])], 1);
        }
    }

    __shared__ float s_pool[4][16], s_stat[4][8];
    __shared__ __align__(16) float g[4][Hn];
    __shared__ float s_part[4][4], s_ss[4];

    // pooling: wave w handles row b0+w
    if (lane < 16) {
        const int b = b0 + w;
        float acc = 0.f, ms = 0.f;
        for (int l = 0; l < 64; l++) {
            float m = mask[b*64 + l];
            ms  += m;
            acc += seq[(b*64 + l)*16 + lane] * m;
        }
        s_pool[w][lane] = acc / fmaxf(ms, 1e-6f);
    } else if (lane < 24) {
        s_stat[w][lane - 16] = stat[(b0 + w)*8 + (lane - 16)];
    }
    __syncthreads();

    // encoder GEMM: thread owns cols h0,h1 for all 4 rows
    {
        float a0[4], a1[4];
        float be0 = b_enc[h0], be1 = b_enc[h1];
        #pragma unroll
        for (int r = 0; r < 4; r++) { a0[r] = be0; a1[r] = be1; }
        #pragma unroll
        for (int j = 0; j < 16; j++) {
            float2 wv = *(const float2*)(W_seq + j*Hn + h0);
            #pragma unroll
            for (int r = 0; r < 4; r++) { a0[r] += s_pool[r][j]*wv.x; a1[r] += s_pool[r][j]*wv.y; }
        }
        #pragma unroll
        for (int j = 0; j < 8; j++) {
            float2 wv = *(const float2*)(W_stat + j*Hn + h0);
            #pragma unroll
            for (int r = 0; r < 4; r++) { a0[r] += s_stat[r][j]*wv.x; a1[r] += s_stat[r][j]*wv.y; }
        }
        #pragma unroll
        for (int r = 0; r < 4; r++) {
            float v0 = fmaxf(a0[r], 0.f), v1 = fmaxf(a1[r], 0.f);
            g[r][h0] = v0; g[r][h1] = v1;
            float* gl = ws + B_OFF + (size_t)(b0 + r)*Hn;
            gl[h0] = v0; gl[h1] = v1;
        }
    }
    __syncthreads();

    // q GEMM: q[r] = g[r] @ W_q + b_q (W_q row read once, used for 4 rows)
    float q0[4], q1[4];
    {
        float bq0 = b_q[h0], bq1 = b_q[h1];
        #pragma unroll
        for (int r = 0; r < 4; r++) { q0[r] = bq0; q1[r] = bq1; }
        #pragma unroll 4
        for (int j = 0; j < Hn; j++) {
            float2 wv = *(const float2*)(W_q + j*Hn + h0);
            #pragma unroll
            for (int r = 0; r < 4; r++) {
                float gj = g[r][j];
                q0[r] += gj*wv.x; q1[r] += gj*wv.y;
            }
        }
    }
    // per-row L2 norm (block reduction, k_fused-proven pattern)
    #pragma unroll
    for (int r = 0; r < 4; r++) {
        float ss = q0[r]*q0[r] + q1[r]*q1[r];
        #pragma unroll
        for (int o = 32; o; o >>= 1) ss += __shfl_xor(ss, o);
        if (lane == 0) s_part[r][w] = ss;
    }
    __syncthreads();
    if (t < 4) s_ss[t] = s_part[t][0] + s_part[t][1] + s_part[t][2] + s_part[t][3];
    __syncthreads();
    #pragma unroll
    for (int r = 0; r < 4; r++) {
        float inv = 1.f / fmaxf(sqrtf(s_ss[r]), 1e-12f);
        float* qr = ws + A_OFF + (size_t)(b0 + r)*Hn;
        qr[h0] = q0[r]*inv; qr[h1] = q1[r]*inv;
    }
}

// ============ K2: fused scan — per-chunk exclusive scan + atomic chunk base; zeroes cursor ============
__global__ __launch_bounds__(256) void k_scan(
    const int* __restrict__ hist, int* __restrict__ offs, int* __restrict__ gtot,
    int* __restrict__ cursor)
{
    __shared__ int s[256]; __shared__ int sbase;
    const int t = threadIdx.x, g = blockIdx.x*256 + t;
    const int v = hist[g];
    cursor[g] = 0;
    s[t] = v; __syncthreads();
    #pragma unroll
    for (int off = 1; off < 256; off <<= 1) {
        int x = (t >= off) ? s[t - off] : 0;
        __syncthreads();
        s[t] += x;
        __syncthreads();
    }
    if (t == 255) sbase = atomicAdd(gtot, s[255]);
    __syncthreads();
    offs[g] = sbase + s[t] - v;   // absolute exclusive offset (chunk order arbitrary)
}

// ============ K3: scatter (b,c) refs into id buckets ============
__global__ __launch_bounds__(256) void k_scatter(
    const int* __restrict__ cand32, int* __restrict__ cursor,
    const int* __restrict__ offs, unsigned* __restrict__ refs)
{
    const int i = blockIdx.x*256 + threadIdx.x;   // i = b*1024 + c
    const int c64 = ((cand32[1] | cand32[3] | cand32[5] | cand32[7]) == 0) ? 1 : 0;
    const int id = clamp_id(cand32[(size_t)i << c64]);
    const int pos = atomicAdd(&cursor[id], 1);
    refs[offs[id] + pos] = (unsigned)i;
}

// ============ K4: GEMM 512x512x512, split-K to 4 partial buffers (no atomics) ============
// grid (8 ct, 8 rt, 4 kz); tile 64r x 64c, K-slice 128; thread 4r x 4c
__global__ __launch_bounds__(256) void k_qgemm_p(
    const float* __restrict__ W, const float* __restrict__ bias,
    const float* __restrict__ in,
    float* __restrict__ P0, float* __restrict__ P1,
    float* __restrict__ P2, float* __restrict__ P3)
{
    const int ct = blockIdx.x, rt = blockIdx.y, kz = blockIdx.z, t = threadIdx.x;
    __shared__ float lt[64][132];
    {   // stage 64 rows x 128 k
        int r = t >> 2, c0 = (t & 3)*32;
        const float* src = in + (size_t)(rt*64 + r)*Hn + kz*128 + c0;
        #pragma unroll
        for (int i = 0; i < 8; i++)
            *(float4*)&lt[r][c0 + i*4] = *(const float4*)(src + i*4);
    }
    __syncthreads();
    const int col0 = ct*64 + (t & 15)*4, rbase = (t >> 4)*4;
    float acc[4][4];
    if (kz == 0) {
        float4 bv = *(const float4*)(bias + col0);
        #pragma unroll
        for (int i = 0; i < 4; i++) { acc[i][0]=bv.x; acc[i][1]=bv.y; acc[i][2]=bv.z; acc[i][3]=bv.w; }
    } else {
        #pragma unroll
        for (int i = 0; i < 4; i++) { acc[i][0]=0; acc[i][1]=0; acc[i][2]=0; acc[i][3]=0; }
    }
    const float* wp = W + (size_t)(kz*128)*Hn + col0;
    #pragma unroll 4
    for (int k = 0; k < 128; k++) {
        float4 wv = *(const float4*)(wp + (size_t)k*Hn);
        #pragma unroll
        for (int i = 0; i < 4; i++) {
            float a = lt[rbase + i][k];
            acc[i][0] += a*wv.x; acc[i][1] += a*wv.y; acc[i][2] += a*wv.z; acc[i][3] += a*wv.w;
        }
    }
    float* outp = (kz == 0) ? P0 : (kz == 1) ? P1 : (kz == 2) ? P2 : P3;
    #pragma unroll
    for (int i = 0; i < 4; i++) {
        float* op = outp + (size_t)(rt*64 + rbase + i)*Hn + col0;
        *(float4*)op = make_float4(acc[i][0], acc[i][1], acc[i][2], acc[i][3]);
    }
}

// ============ K5: inverted-index sim — nt key stream, predicated tail (R3 proven) ============
#define DI_LOAD(R0,R1,R2,R3,A0,Bq0,A1,Bq1,A2,Bq2,A3,Bq3,BASE) do {                       \
    int j0_=(BASE), j1_=(BASE)+1, j2_=(BASE)+2, j3_=(BASE)+3;                            \
    const int m_ = n - 1;                                                                \
    const int c1_ = (j1_ < n), c2_ = (j2_ < n), c3_ = (j3_ < n);                         \
    j0_ = j0_>m_?m_:j0_; j1_ = j1_>m_?m_:j1_; j2_ = j2_>m_?m_:j2_; j3_ = j3_>m_?m_:j3_;  \
    R0 = (j0_<64)?(unsigned)__shfl((int)refv,j0_):__builtin_nontemporal_load(refs+start+j0_); \
    R1 = (j1_<64)?(unsigned)__shfl((int)refv,j1_):__builtin_nontemporal_load(refs+start+j1_); \
    R2 = (j2_<64)?(unsigned)__shfl((int)refv,j2_):__builtin_nontemporal_load(refs+start+j2_); \
    R3 = (j3_<64)?(unsigned)__shfl((int)refv,j3_):__builtin_nontemporal_load(refs+start+j3_); \
    {   const float* q0_ = qbase + (size_t)(R0>>10)*Hn + lane*8;                         \
        A0 = *(const float4*)q0_; Bq0 = *(const float4*)(q0_+4); }                       \
    if (c1_) { const float* q1_ = qbase + (size_t)(R1>>10)*Hn + lane*8;                  \
        A1 = *(const float4*)q1_; Bq1 = *(const float4*)(q1_+4); }                       \
    if (c2_) { const float* q2_ = qbase + (size_t)(R2>>10)*Hn + lane*8;                  \
        A2 = *(const float4*)q2_; Bq2 = *(const float4*)(q2_+4); }                       \
    if (c3_) { const float* q3_ = qbase + (size_t)(R3>>10)*Hn + lane*8;                  \
        A3 = *(const float4*)q3_; Bq3 = *(const float4*)(q3_+4); }                       \
} while(0)

#define DI_COMP(R0,R1,R2,R3,A0,Bq0,A1,Bq1,A2,Bq2,A3,Bq3,BASE) do {                       \
    float s0_ = ka.x*A0.x + ka.y*A0.y + ka.z*A0.z + ka.w*A0.w                            \
              + kb.x*Bq0.x + kb.y*Bq0.y + kb.z*Bq0.z + kb.w*Bq0.w;                       \
    float s1_ = ka.x*A1.x + ka.y*A1.y + ka.z*A1.z + ka.w*A1.w                            \
              + kb.x*Bq1.x + kb.y*Bq1.y + kb.z*Bq1.z + kb.w*Bq1.w;                       \
    float s2_ = ka.x*A2.x + ka.y*A2.y + ka.z*A2.z + ka.w*A2.w                            \
              + kb.x*Bq2.x + kb.y*Bq2.y + kb.z*Bq2.z + kb.w*Bq2.w;                       \
    float s3_ = ka.x*A3.x + ka.y*A3.y + ka.z*A3.z + ka.w*A3.w                            \
              + kb.x*Bq3.x + kb.y*Bq3.y + kb.z*Bq3.z + kb.w*Bq3.w;                       \
    s0_ += __shfl_xor(s0_,32); s1_ += __shfl_xor(s1_,32);                                \
    s2_ += __shfl_xor(s2_,32); s3_ += __shfl_xor(s3_,32);                                \
    s0_ += __shfl_xor(s0_,16); s1_ += __shfl_xor(s1_,16);                                \
    s2_ += __shfl_xor(s2_,16); s3_ += __shfl_xor(s3_,16);                                \
    s0_ += __shfl_xor(s0_, 8); s1_ += __shfl_xor(s1_, 8);                                \
    s2_ += __shfl_xor(s2_, 8); s3_ += __shfl_xor(s3_, 8);                                \
    int d_ = (lane >> 3) & 3;                                                            \
    float t_ = d_==0 ? s0_ : d_==1 ? s1_ : d_==2 ? s2_ : s3_;                            \
    t_ += __shfl_xor(t_, 4); t_ += __shfl_xor(t_, 2); t_ += __shfl_xor(t_, 1);           \
    if ((lane & 7) == 0 && lane < 32) {                                                  \
        int dd_ = lane >> 3;                                                             \
        if ((BASE) + dd_ < n) {                                                          \
            unsigned rs_ = dd_==0 ? R0 : dd_==1 ? R1 : dd_==2 ? R2 : R3;                 \
            simw[rs_] = t_;                                                              \
        }                                                                                \
    }                                                                                    \
} while(0)

__global__ __launch_bounds__(256) void k_dotinv(
    const float* __restrict__ bank_keys, const unsigned* __restrict__ refs,
    const int* __restrict__ offs, const int* __restrict__ cnt,
    float* __restrict__ ws)
{
    const int id = blockIdx.x*4 + (threadIdx.x >> 6);
    const int lane = threadIdx.x & 63;
    const int n = cnt[id];
    if (n <= 0) return;
    const int start = offs[id];

    const float* kp = bank_keys + (size_t)id*Hn + lane*8;
    f4v kav = __builtin_nontemporal_load((const f4v*)kp);
    f4v kbv = __builtin_nontemporal_load((const f4v*)(kp + 4));
    float4 ka = make_float4(kav.x, kav.y, kav.z, kav.w);
    float4 kb = make_float4(kbv.x, kbv.y, kbv.z, kbv.w);
    const unsigned refv = refs[start + (lane < n ? lane : n - 1)];
    const float* qbase = ws + A_OFF;
    float* simw = ws + SIM_OFF;

    unsigned Ar0,Ar1,Ar2,Ar3, Br0=0,Br1=0,Br2=0,Br3=0;
    float4 Aa0,Ab0,Aa1,Ab1,Aa2,Ab2,Aa3,Ab3;
    float4 Ba0,Bb0,Ba1,Bb1,Ba2,Bb2,Ba3,Bb3;
    Aa0=Ab0=Aa1=Ab1=Aa2=Ab2=Aa3=Ab3=make_float4(0.f,0.f,0.f,0.f);
    Ba0=Bb0=Ba1=Bb1=Ba2=Bb2=Ba3=Bb3=make_float4(0.f,0.f,0.f,0.f);

    DI_LOAD(Ar0,Ar1,Ar2,Ar3, Aa0,Ab0,Aa1,Ab1,Aa2,Ab2,Aa3,Ab3, 0);
    for (int base = 0; ; ) {
        if (base + 4 < n) DI_LOAD(Br0,Br1,Br2,Br3, Ba0,Bb0,Ba1,Bb1,Ba2,Bb2,Ba3,Bb3, base + 4);
        DI_COMP(Ar0,Ar1,Ar2,Ar3, Aa0,Ab0,Aa1,Ab1,Aa2,Ab2,Aa3,Ab3, base);
        if (base + 8 < n) DI_LOAD(Ar0,Ar1,Ar2,Ar3, Aa0,Ab0,Aa1,Ab1,Aa2,Ab2,Aa3,Ab3, base + 8);
        DI_COMP(Br0,Br1,Br2,Br3, Ba0,Bb0,Ba1,Bb1,Ba2,Bb2,Ba3,Bb3, base + 4);
        base += 8;
        if (base >= n) break;
    }
}

// ============ K6: top-16 + softmax + donor + proto ============
__global__ __launch_bounds__(256) void k_select(
    const float* __restrict__ bank_values, const int* __restrict__ cand32,
    const float* __restrict__ proto, float* __restrict__ ws)
{
    const int b = blockIdx.x, t = threadIdx.x;
    const int w = t >> 6, lane = t & 63;
    const int h0 = 2*t, h1 = 2*t + 1;
    const int c64 = ((cand32[1] | cand32[3] | cand32[5] | cand32[7]) == 0) ? 1 : 0;

    __shared__ __align__(16) float s_sim[Cn];
    __shared__ float s_bv[4]; __shared__ int s_bi[4];
    __shared__ float s_topv[Kn]; __shared__ int s_sel[Kn];
    __shared__ float s_w[Kn];
    __shared__ float s_score[8], s_pw[8];

    *(float4*)&s_sim[t*4] = *(const float4*)(ws + SIM_OFF + (size_t)b*Cn + t*4);

    const float* qr = ws + A_OFF + (size_t)b*Hn + lane*8;
    float4 qa = *(const float4*)qr, qb = *(const float4*)(qr + 4);
    float qv[8] = {qa.x, qa.y, qa.z, qa.w, qb.x, qb.y, qb.z, qb.w};
    __syncthreads();

    for (int k = 0; k < Kn; k++) {
        float best = -1e30f; int bi = 0x7fffffff;
        for (int i = t; i < Cn; i += 256) {
            float v = s_sim[i];
            if (v > best || (v == best && i < bi)) { best = v; bi = i; }
        }
        #pragma unroll
        for (int o = 32; o; o >>= 1) {
            float ov = __shfl_xor(best, o); int oi = __shfl_xor(bi, o);
            if (ov > best || (ov == best && oi < bi)) { best = ov; bi = oi; }
        }
        if (lane == 0) { s_bv[w] = best; s_bi[w] = bi; }
        __syncthreads();
        if (t == 0) {
            float bv = s_bv[0]; int bbi = s_bi[0];
            for (int x = 1; x < 4; x++)
                if (s_bv[x] > bv || (s_bv[x] == bv && s_bi[x] < bbi)) { bv = s_bv[x]; bbi = s_bi[x]; }
            if (bbi < 0 || bbi >= Cn) bbi = 0;
            s_topv[k] = bv; s_sel[k] = bbi; s_sim[bbi] = -1e30f;
        }
        __syncthreads();
    }

    if (t == 0) {
        float m = s_topv[0];
        float e[Kn], ssum = 0.f;
        for (int k = 0; k < Kn; k++) { e[k] = __expf((s_topv[k] - m) * 5.0f); ssum += e[k]; }
        float inv = 1.f / ssum;
        for (int k = 0; k < Kn; k++) s_w[k] = e[k] * inv;
    }
    for (int p = w; p < 8; p += 4) {
        const float* pp = proto + (size_t)p*Hn + lane*8;
        float4 pa = *(const float4*)pp, pb = *(const float4*)(pp + 4);
        float f[8] = {pa.x, pa.y, pa.z, pa.w, pb.x, pb.y, pb.z, pb.w};
        float dq = 0.f, sq = 0.f;
        #pragma unroll
        for (int i = 0; i < 8; i++) { dq += f[i]*qv[i]; sq += f[i]*f[i]; }
        #pragma unroll
        for (int o = 32; o; o >>= 1) { dq += __shfl_xor(dq, o); sq += __shfl_xor(sq, o); }
        if (lane == 0) s_score[p] = dq / fmaxf(sqrtf(sq), 1e-12f);
    }
    __syncthreads();
    if (t == 0) {
        float m = s_score[0];
        for (int p = 1; p < 8; p++) m = fmaxf(m, s_score[p]);
        float e[8], ssum = 0.f;
        for (int p = 0; p < 8; p++) { e[p] = __expf(s_score[p] - m); ssum += e[p]; }
        float inv = 1.f / ssum;
        for (int p = 0; p < 8; p++) s_pw[p] = e[p] * inv;
    }
    __syncthreads();

    {
        float a0 = 0.f, a1 = 0.f;
        #pragma unroll
        for (int k = 0; k < Kn; k++) {
            int id = clamp_id(cand32[(size_t)(b*Cn + s_sel[k]) << c64]);
            f2v v = __builtin_nontemporal_load((const f2v*)(bank_values + (size_t)id*Hn + h0));
            a0 += s_w[k]*v.x; a1 += s_w[k]*v.y;
        }
        float* gd = ws + C_OFF + (size_t)b*Hn;
        gd[h0] = a0; gd[h1] = a1;
    }
    {
        float a0 = 0.f, a1 = 0.f;
        #pragma unroll
        for (int p = 0; p < 8; p++) {
            float2 v = *(const float2*)(proto + (size_t)p*Hn + h0);
            a0 += s_pw[p]*v.x; a1 += s_pw[p]*v.y;
        }
        float* gp = ws + D_OFF + (size_t)b*Hn;
        gp[h0] = a0; gp[h1] = a1;
    }
}

// ============ K7: gate/tr -> 5 partial buffers (no atomics) ============
// grid (4 ct, 16 rt, 5 z): z<3 gate K-slice z (K=512 = slab z); z>=3 tr slice z-3
__global__ __launch_bounds__(256) void k_gatetr_p(
    const float* __restrict__ W_tr, const float* __restrict__ b_tr,
    const float* __restrict__ W_gate, const float* __restrict__ b_gate,
    float* __restrict__ ws)
{
    const int ct = blockIdx.x, rt = blockIdx.y, z = blockIdx.z, t = threadIdx.x;
    const int isGate = (z < 3);
    const int sl = isGate ? z : (z - 3);
    const float* W = isGate ? (W_gate + (size_t)(z*512)*Hn) : (W_tr + (size_t)(sl*512)*Hn);
    const float* slab = ws + B_OFF + (size_t)(isGate ? z : (sl + 1))*262144;
    float* outp = isGate
        ? ((z == 0) ? ws + A_OFF : (z == 1) ? ws + ELO_OFF : ws + EHI_OFF)
        : ((sl == 0) ? ws + F_OFF : ws + G_OFF2);

    __shared__ float lt[32][260];
    const int col0 = ct*128 + (t & 31)*4, rbase = (t >> 5)*4;
    float acc[4][4];
    if (z == 0 || z == 3) {
        const float* bias = isGate ? b_gate : b_tr;
        float4 bv = *(const float4*)(bias + col0);
        #pragma unroll
        for (int i = 0; i < 4; i++) { acc[i][0]=bv.x; acc[i][1]=bv.y; acc[i][2]=bv.z; acc[i][3]=bv.w; }
    } else {
        #pragma unroll
        for (int i = 0; i < 4; i++) { acc[i][0]=0; acc[i][1]=0; acc[i][2]=0; acc[i][3]=0; }
    }

    #pragma unroll
    for (int h = 0; h < 2; h++) {
        if (h) __syncthreads();
        {   // stage 32 rows x 256 k
            int r = t >> 3, c0 = (t & 7)*32;
            const float* src = slab + (size_t)(rt*32 + r)*Hn + h*256 + c0;
            #pragma unroll
            for (int i = 0; i < 8; i++)
                *(float4*)&lt[r][c0 + i*4] = *(const float4*)(src + i*4);
        }
        __syncthreads();
        const float* wp = W + (size_t)(h*256)*Hn + col0;
        #pragma unroll 4
        for (int k = 0; k < 256; k++) {
            float4 wv = *(const float4*)(wp + (size_t)k*Hn);
            #pragma unroll
            for (int i = 0; i < 4; i++) {
                float a = lt[rbase + i][k];
                acc[i][0] += a*wv.x; acc[i][1] += a*wv.y; acc[i][2] += a*wv.z; acc[i][3] += a*wv.w;
            }
        }
    }
    #pragma unroll
    for (int i = 0; i < 4; i++) {
        float* op = outp + (size_t)(rt*32 + rbase + i)*Hn + col0;
        *(float4*)op = make_float4(acc[i][0], acc[i][1], acc[i][2], acc[i][3]);
    }
}

// ============ K8: f1 = sigmoid(Σgate)*local + (1-sig)*relu(Σtr) -> A ============
__global__ __launch_bounds__(256) void k_f1ew(float* __restrict__ ws)
{
    const int i4 = blockIdx.x*256 + threadIdx.x;   // 65536 float4s
    const size_t off = (size_t)(i4 >> 7)*Hn + (i4 & 127)*4;
    float4 lc = *(const float4*)(ws + B_OFF + off);
    float4 g0 = *(const float4*)(ws + A_OFF + off);
    float4 g1 = *(const float4*)(ws + ELO_OFF + off);
    float4 g2 = *(const float4*)(ws + EHI_OFF + off);
    float4 t0 = *(const float4*)(ws + F_OFF + off);
    float4 t1 = *(const float4*)(ws + G_OFF2 + off);
    float4 ga = make_float4((g0.x+g1.x)+g2.x, (g0.y+g1.y)+g2.y,
                            (g0.z+g1.z)+g2.z, (g0.w+g1.w)+g2.w);
    float4 tr = make_float4(t0.x+t1.x, t0.y+t1.y, t0.z+t1.z, t0.w+t1.w);
    float4 r;
    float s;
    s = 1.f/(1.f + __expf(-ga.x)); r.x = s*lc.x + (1.f-s)*fmaxf(tr.x, 0.f);
    s = 1.f/(1.f + __expf(-ga.y)); r.y = s*lc.y + (1.f-s)*fmaxf(tr.y, 0.f);
    s = 1.f/(1.f + __expf(-ga.z)); r.z = s*lc.z + (1.f-s)*fmaxf(tr.z, 0.f);
    s = 1.f/(1.f + __expf(-ga.w)); r.w = s*lc.w + (1.f-s)*fmaxf(tr.w, 0.f);
    *(float4*)(ws + A_OFF + off) = r;
}

// ============ K9: heads (sums 4 f2-partials, relu, project) ============
__global__ __launch_bounds__(64) void k_heads(
    const float* __restrict__ W_quant, const float* __restrict__ b_quant,
    const float* __restrict__ W_ev, const float* __restrict__ b_ev,
    const float* __restrict__ ws_ro, float* __restrict__ out)
{
    const int b = blockIdx.x, lane = threadIdx.x;
    const size_t o = (size_t)b*Hn + lane*8;
    const float* p0 = ws_ro + ELO_OFF + o;
    const float* p1 = ws_ro + EHI_OFF + o;
    const float* p2 = ws_ro + F_OFF + o;
    const float* p3 = ws_ro + G_OFF2 + o;
    float4 a0 = *(const float4*)p0, a1 = *(const float4*)p1,
           a2 = *(const float4*)p2, a3 = *(const float4*)p3;
    float4 b0 = *(const float4*)(p0+4), b1 = *(const float4*)(p1+4),
           b2 = *(const float4*)(p2+4), b3 = *(const float4*)(p3+4);
    float fv[8] = {
        fmaxf(((a0.x+a1.x)+a2.x)+a3.x, 0.f), fmaxf(((a0.y+a1.y)+a2.y)+a3.y, 0.f),
        fmaxf(((a0.z+a1.z)+a2.z)+a3.z, 0.f), fmaxf(((a0.w+a1.w)+a2.w)+a3.w, 0.f),
        fmaxf(((b0.x+b1.x)+b2.x)+b3.x, 0.f), fmaxf(((b0.y+b1.y)+b2.y)+b3.y, 0.f),
        fmaxf(((b0.z+b1.z)+b2.z)+b3.z, 0.f), fmaxf(((b0.w+b1.w)+b2.w)+b3.w, 0.f)};
    float acc[8];
    #pragma unroll
    for (int q = 0; q < 8; q++) acc[q] = 0.f;
    #pragma unroll
    for (int i = 0; i < 8; i++) {
        int h = lane*8 + i;
        float fh = fv[i];
        acc[0] += fh*W_quant[(0*Hn + h)*3 + 0];
        acc[1] += fh*W_quant[(0*Hn + h)*3 + 1];
        acc[2] += fh*W_quant[(0*Hn + h)*3 + 2];
        acc[3] += fh*W_quant[(1*Hn + h)*3 + 0];
        acc[4] += fh*W_quant[(1*Hn + h)*3 + 1];
        acc[5] += fh*W_quant[(1*Hn + h)*3 + 2];
        acc[6] += fh*W_ev[0*Hn + h];
        acc[7] += fh*W_ev[1*Hn + h];
    }
    #pragma unroll
    for (int q = 0; q < 8; q++) {
        #pragma unroll
        for (int s = 32; s; s >>= 1) acc[q] += __shfl_xor(acc[q], s);
    }
    if (lane == 0) {
        float qv[6];
        for (int q = 0; q < 6; q++) qv[q] = acc[q] + b_quant[q];
        #pragma unroll
        for (int tt = 0; tt < 2; tt++) {
            float a = qv[tt*3], bb = qv[tt*3+1], c = qv[tt*3+2];
            float mn = fminf(a, fminf(bb, c)), mx = fmaxf(a, fmaxf(bb, c));
            float md = a + bb + c - mn - mx;
            qv[tt*3] = mn; qv[tt*3+1] = md; qv[tt*3+2] = mx;
        }
        for (int q = 0; q < 6; q++) out[b*8 + q] = qv[q];
        out[b*8 + 6] = acc[6] + b_ev[0];
        out[b*8 + 7] = acc[7] + b_ev[1];
    }
}

// ===================== Fallback: proven R4 fused kernel =====================
__device__ __forceinline__ float lds_f(const void* p, int i, int f32){
    return f32 ? ((const float*)p)[i] : __bfloat162float(((const bf16*)p)[i]);
}
__device__ __forceinline__ float2 ldpair(const void* p, int elt, int f32){
    if (f32) return ((const float2*)p)[elt >> 1];
    unsigned u = ((const unsigned*)p)[elt >> 1];
    return make_float2(lo16(u), hi16(u));
}
__device__ __forceinline__ void ld8(const void* p, int elt, int f32, float* v){
    if (f32){
        const float4* q = (const float4*)((const float*)p + elt);
        float4 a = q[0], b = q[1];
        v[0]=a.x; v[1]=a.y; v[2]=a.z; v[3]=a.w; v[4]=b.x; v[5]=b.y; v[6]=b.z; v[7]=b.w;
    } else {
        uint4 u = *(const uint4*)((const bf16*)p + elt);
        v[0]=lo16(u.x); v[1]=hi16(u.x); v[2]=lo16(u.y); v[3]=hi16(u.y);
        v[4]=lo16(u.z); v[5]=hi16(u.z); v[6]=lo16(u.w); v[7]=hi16(u.w);
    }
}
__device__ __forceinline__ void st_out(void* o, int i, int f32, float v){
    if (f32) ((float*)o)[i] = v; else ((bf16*)o)[i] = __float2bfloat16(v);
}

__global__ __launch_bounds__(256) void k_fused(
    const void* __restrict__ seq, const void* __restrict__ mask, const void* __restrict__ stat,
    const void* __restrict__ bank_keys, const void* __restrict__ bank_values,
    const int* __restrict__ cand32,
    const void* __restrict__ W_seq, const void* __restrict__ W_stat, const void* __restrict__ b_enc,
    const void* __restrict__ W_q, const void* __restrict__ b_q,
    const void* __restrict__ proto,
    const void* __restrict__ W_tr, const void* __restrict__ b_tr,
    const void* __restrict__ W_gate, const void* __restrict__ b_gate,
    const void* __restrict__ W_out, const void* __restrict__ b_out,
    const void* __restrict__ W_quant, const void* __restrict__ b_quant,
    const void* __restrict__ W_ev, const void* __restrict__ b_ev,
    void* __restrict__ out)
{
    const int b = blockIdx.x, t = threadIdx.x;
    const int w = t >> 6, lane = t & 63;
    const int h0 = 2*t, h1 = 2*t + 1;
    const int f32 = (((const unsigned short*)mask)[0] == 0) ? 1 : 0;
    const int c64 = ((cand32[1] | cand32[3] | cand32[5] | cand32[7]) == 0) ? 1 : 0;

    __shared__ __align__(16) float s_pool[16];
    __shared__ __align__(16) float s_stat[8];
    __shared__ __align__(16) float g[1536];
    __shared__ __align__(16) float s_q[Hn];
    __shared__ __align__(16) float s_sim[Cn];
    __shared__ __align__(16) float f1[Hn];
    __shared__ __align__(16) float f2[Hn];
    __shared__ float s_part[4], s_ss;
    __shared__ float s_bv[4]; __shared__ int s_bi[4];
    __shared__ float s_topv[Kn]; __shared__ int s_sel[Kn];
    __shared__ float s_w[Kn];
    __shared__ float s_score[8], s_pw[8];
    __shared__ float s_head[8][4];

    if (t < 16) {
        float acc = 0.f, ms = 0.f;
        for (int l = 0; l < 64; l++) {
            float m = lds_f(mask, b*64 + l, f32);
            ms  += m;
            acc += lds_f(seq, (b*64 + l)*16 + t, f32) * m;
        }
        s_pool[t] = acc / fmaxf(ms, 1e-6f);
    } else if (t < 24) {
        s_stat[t - 16] = lds_f(stat, b*8 + (t - 16), f32);
    }
    __syncthreads();
    {
        float a0 = lds_f(b_enc, h0, f32), a1 = lds_f(b_enc, h1, f32);
        #pragma unroll
        for (int j = 0; j < 16; j++) {
            float2 wv = ldpair(W_seq, j*Hn + h0, f32);
            a0 += s_pool[j]*wv.x; a1 += s_pool[j]*wv.y;
        }
        #pragma unroll
        for (int j = 0; j < 8; j++) {
            float2 wv = ldpair(W_stat, j*Hn + h0, f32);
            a0 += s_stat[j]*wv.x; a1 += s_stat[j]*wv.y;
        }
        a0 = fmaxf(a0, 0.f); a1 = fmaxf(a1, 0.f);
        g[h0] = a0; g[h1] = a1;
    }
    __syncthreads();
    {
        float q0 = lds_f(b_q, h0, f32), q1 = lds_f(b_q, h1, f32);
        #pragma unroll 4
        for (int j = 0; j < Hn; j++) {
            float lj = g[j];
            float2 wv = ldpair(W_q, j*Hn + h0, f32);
            q0 += lj*wv.x; q1 += lj*wv.y;
        }
        float ss = q0*q0 + q1*q1;
        #pragma unroll
        for (int o = 32; o; o >>= 1) ss += __shfl_xor(ss, o);
        if (lane == 0) s_part[w] = ss;
        __syncthreads();
        if (t == 0) s_ss = s_part[0] + s_part[1] + s_part[2] + s_part[3];
        __syncthreads();
        float inv = 1.f / fmaxf(sqrtf(s_ss), 1e-12f);
        s_q[h0] = q0*inv; s_q[h1] = q1*inv;
    }
    __syncthreads();
    float qv[8];
    #pragma unroll
    for (int i = 0; i < 8; i++) qv[i] = s_q[lane*8 + i];

    for (int c0 = w*256; c0 < w*256 + 256; c0 += 4) {
        float kf[4][8];
        #pragma unroll
        for (int u = 0; u < 4; u++) {
            int id = clamp_id(cand32[(size_t)(b*Cn + c0 + u) << c64]);
            ld8(bank_keys, id*Hn + lane*8, f32, kf[u]);
        }
        #pragma unroll
        for (int u = 0; u < 4; u++) {
            float s = 0.f;
            #pragma unroll
            for (int i = 0; i < 8; i++) s += kf[u][i]*qv[i];
            #pragma unroll
            for (int o = 32; o; o >>= 1) s += __shfl_xor(s, o);
            if (lane == 0) s_sim[c0 + u] = s;
        }
    }
    __syncthreads();
    for (int k = 0; k < Kn; k++) {
        float best = -1e30f; int bi = 0x7fffffff;
        for (int i = t; i < Cn; i += 256) {
            float v = s_sim[i];
            if (v > best || (v == best && i < bi)) { best = v; bi = i; }
        }
        #pragma unroll
        for (int o = 32; o; o >>= 1) {
            float ov = __shfl_xor(best, o); int oi = __shfl_xor(bi, o);
            if (ov > best || (ov == best && oi < bi)) { best = ov; bi = oi; }
        }
        if (lane == 0) { s_bv[w] = best; s_bi[w] = bi; }
        __syncthreads();
        if (t == 0) {
            float bv = s_bv[0]; int bbi = s_bi[0];
            for (int x = 1; x < 4; x++)
                if (s_bv[x] > bv || (s_bv[x] == bv && s_bi[x] < bbi)) { bv = s_bv[x]; bbi = s_bi[x]; }
            if (bbi < 0 || bbi >= Cn) bbi = 0;
            s_topv[k] = bv; s_sel[k] = bbi; s_sim[bbi] = -1e30f;
        }
        __syncthreads();
    }
    if (t == 0) {
        float m = s_topv[0];
        float e[Kn], ssum = 0.f;
        for (int k = 0; k < Kn; k++) { e[k] = __expf((s_topv[k] - m) * 5.0f); ssum += e[k]; }
        float inv = 1.f / ssum;
        for (int k = 0; k < Kn; k++) s_w[k] = e[k] * inv;
    }
    __syncthreads();
    {
        float a0 = 0.f, a1 = 0.f;
        #pragma unroll
        for (int k = 0; k < Kn; k++) {
            int id = clamp_id(cand32[(size_t)(b*Cn + s_sel[k]) << c64]);
            float2 v = ldpair(bank_values, id*Hn + h0, f32);
            a0 += s_w[k]*v.x; a1 += s_w[k]*v.y;
        }
        g[512 + h0] = a0; g[512 + h1] = a1;
    }
    for (int p = w; p < 8; p += 4) {
        float f[8];
        ld8(proto, p*Hn + lane*8, f32, f);
        float dq = 0.f, sq = 0.f;
        #pragma unroll
        for (int i = 0; i < 8; i++) { dq += f[i]*qv[i]; sq += f[i]*f[i]; }
        #pragma unroll
        for (int o = 32; o; o >>= 1) { dq += __shfl_xor(dq, o); sq += __shfl_xor(sq, o); }
        if (lane == 0) s_score[p] = dq / fmaxf(sqrtf(sq), 1e-12f);
    }
    __syncthreads();
    if (t == 0) {
        float m = s_score[0];
        for (int p = 1; p < 8; p++) m = fmaxf(m, s_score[p]);
        float e[8], ssum = 0.f;
        for (int p = 0; p < 8; p++) { e[p] = __expf(s_score[p] - m); ssum += e[p]; }
        float inv = 1.f / ssum;
        for (int p = 0; p < 8; p++) s_pw[p] = e[p] * inv;
    }
    __syncthreads();
    {
        float a0 = 0.f, a1 = 0.f;
        #pragma unroll
        for (int p = 0; p < 8; p++) {
            float2 v = ldpair(proto, p*Hn + h0, f32);
            a0 += s_pw[p]*v.x; a1 += s_pw[p]*v.y;
        }
        g[1024 + h0] = a0; g[1024 + h1] = a1;
    }
    __syncthreads();
    float tr0 = lds_f(b_tr, h0, f32), tr1 = lds_f(b_tr, h1, f32);
    #pragma unroll 4
    for (int j = 0; j < 1024; j++) {
        float gj = g[512 + j];
        float2 wv = ldpair(W_tr, j*Hn + h0, f32);
        tr0 += gj*wv.x; tr1 += gj*wv.y;
    }
    tr0 = fmaxf(tr0, 0.f); tr1 = fmaxf(tr1, 0.f);
    float gt0 = lds_f(b_gate, h0, f32), gt1 = lds_f(b_gate, h1, f32);
    #pragma unroll 4
    for (int j = 0; j < 1536; j++) {
        float gj = g[j];
        float2 wv = ldpair(W_gate, j*Hn + h0, f32);
        gt0 += gj*wv.x; gt1 += gj*wv.y;
    }
    gt0 = 1.f/(1.f + __expf(-gt0)); gt1 = 1.f/(1.f + __expf(-gt1));
    f1[h0] = gt0*g[h0] + (1.f - gt0)*tr0;
    f1[h1] = gt1*g[h1] + (1.f - gt1)*tr1;
    __syncthreads();
    {
        float o0 = lds_f(b_out, h0, f32), o1 = lds_f(b_out, h1, f32);
        #pragma unroll 4
        for (int j = 0; j < Hn; j++) {
            float fj = f1[j];
            float2 wv = ldpair(W_out, j*Hn + h0, f32);
            o0 += fj*wv.x; o1 += fj*wv.y;
        }
        o0 = fmaxf(o0, 0.f); o1 = fmaxf(o1, 0.f);
        f2[h0] = o0; f2[h1] = o1;
    }
    __syncthreads();
    {
        float acc[8];
        #pragma unroll
        for (int o = 0; o < 8; o++) acc[o] = 0.f;
        for (int h = t; h < Hn; h += 256) {
            float fh = f2[h];
            acc[0] += fh*lds_f(W_quant, (0*Hn + h)*3 + 0, f32);
            acc[1] += fh*lds_f(W_quant, (0*Hn + h)*3 + 1, f32);
            acc[2] += fh*lds_f(W_quant, (0*Hn + h)*3 + 2, f32);
            acc[3] += fh*lds_f(W_quant, (1*Hn + h)*3 + 0, f32);
            acc[4] += fh*lds_f(W_quant, (1*Hn + h)*3 + 1, f32);
            acc[5] += fh*lds_f(W_quant, (1*Hn + h)*3 + 2, f32);
            acc[6] += fh*lds_f(W_ev, 0*Hn + h, f32);
            acc[7] += fh*lds_f(W_ev, 1*Hn + h, f32);
        }
        #pragma unroll
        for (int o = 0; o < 8; o++) {
            float v = acc[o];
            #pragma unroll
            for (int s = 32; s; s >>= 1) v += __shfl_xor(v, s);
            if (lane == 0) s_head[o][w] = v;
        }
        __syncthreads();
        if (t == 0) {
            float q[6];
            for (int o = 0; o < 6; o++)
                q[o] = s_head[o][0] + s_head[o][1] + s_head[o][2] + s_head[o][3] + lds_f(b_quant, o, f32);
            #pragma unroll
            for (int tt = 0; tt < 2; tt++) {
                float a = q[tt*3], bb = q[tt*3+1], c = q[tt*3+2];
                float mn = fminf(a, fminf(bb, c)), mx = fmaxf(a, fmaxf(bb, c));
                float md = a + bb + c - mn - mx;
                q[tt*3] = mn; q[tt*3+1] = md; q[tt*3+2] = mx;
            }
            for (int o = 0; o < 6; o++) st_out(out, b*8 + o, f32, q[o]);
            float l0 = s_head[6][0] + s_head[6][1] + s_head[6][2] + s_head[6][3] + lds_f(b_ev, 0, f32);
            float l1 = s_head[7][0] + s_head[7][1] + s_head[7][2] + s_head[7][3] + lds_f(b_ev, 1, f32);
            st_out(out, b*8 + 6, f32, l0);
            st_out(out, b*8 + 7, f32, l1);
        }
    }
}

extern "C" void kernel_launch(void* const* d_in, const int* in_sizes, int n_in,
                              void* d_out, int out_size, void* d_ws, size_t ws_size,
                              hipStream_t stream) {
    static const int expect[22] = {
        512*64*16, 512*64, 512*8, 50000*512, 50000*512, 512*1024,
        16*512, 8*512, 512, 512*512, 512, 8*512,
        1024*512, 512, 1536*512, 512, 512*512, 512,
        2*512*3, 2*3, 2*512, 2
    };
    if (n_in != 22 || out_size != 512*8) return;
    for (int i = 0; i < 22; i++) if (in_sizes[i] != expect[i]) return;

    if (ws_size < (size_t)WS_FLOATS * 4) {
        k_fused<<<Bn, 256, 0, stream>>>(
            d_in[0], d_in[1], d_in[2], d_in[3], d_in[4], (const int*)d_in[5],
            d_in[6], d_in[7], d_in[8], d_in[9], d_in[10], d_in[11],
            d_in[12], d_in[13], d_in[14], d_in[15], d_in[16], d_in[17],
            d_in[18], d_in[19], d_in[20], d_in[21], d_out);
        return;
    }

    float* ws = (float*)d_ws;
    int* iws = (int*)(ws + F_OFF);
    int* hist   = iws + HIST_I;
    int* gtot   = iws + GTOT_I;
    int* cursor = iws + CURSOR_I;
    int* offs   = iws + OFFS_I;
    unsigned* refs = (unsigned*)(ws + C_OFF);   // 2 MB (C+D slabs, dead until k_select)

    // single memset: hist + gtot (cursor is zeroed by k_scan)
    hipMemsetAsync(iws, 0, (size_t)(NIDPAD + 256)*4, stream);

    k_encq<<<Bn/4, 256, 0, stream>>>(
        (const float*)d_in[0], (const float*)d_in[1], (const float*)d_in[2],
        (const float*)d_in[6], (const float*)d_in[7], (const float*)d_in[8],
        (const float*)d_in[9], (const float*)d_in[10],
        (const int*)d_in[5], ws);
    k_scan<<<NIDPAD/256, 256, 0, stream>>>(hist, offs, gtot, cursor);
    k_scatter<<<(Bn*Cn)/256, 256, 0, stream>>>((const int*)d_in[5], cursor, offs, refs);
    k_dotinv<<<NBANK/4, 256, 0, stream>>>((const float*)d_in[3], refs, offs, hist, ws);
    k_select<<<Bn, 256, 0, stream>>>((const float*)d_in[4], (const int*)d_in[5],
                                     (const float*)d_in[11], ws);
    k_gatetr_p<<<dim3(4, 16, 5), 256, 0, stream>>>(
        (const float*)d_in[12], (const float*)d_in[13],
        (const float*)d_in[14], (const float*)d_in[15], ws);
    k_f1ew<<<256, 256, 0, stream>>>(ws);
    k_qgemm_p<<<dim3(8, 8, 4), 256, 0, stream>>>(
        (const float*)d_in[16], (const float*)d_in[17], ws + A_OFF,
        ws + ELO_OFF, ws + EHI_OFF, ws + F_OFF, ws + G_OFF2);
    k_heads<<<Bn, 64, 0, stream>>>((const float*)d_in[18], (const float*)d_in[19],
                                   (const float*)d_in[20], (const float*)d_in[21],
                                   ws, (float*)d_out);
}